// Round 3
// baseline (295.419 us; speedup 1.0000x reference)
//
#include <hip/hip_runtime.h>
#include <hip/hip_bf16.h>
#include <math.h>

typedef unsigned short ushort_t;
typedef __attribute__((ext_vector_type(8))) unsigned short ushort8;
typedef __attribute__((ext_vector_type(4))) unsigned short ushort4_t;
typedef __attribute__((ext_vector_type(8))) __bf16 bf16x8;
typedef __attribute__((ext_vector_type(4))) float f32x4;

__device__ inline ushort_t f2b(float f) {
  __hip_bfloat16 h = __float2bfloat16(f);
  return __builtin_bit_cast(ushort_t, h);
}
__device__ inline float b2f(ushort_t u) {
  __hip_bfloat16 h = __builtin_bit_cast(__hip_bfloat16, u);
  return __bfloat162float(h);
}

__device__ inline void gload16(const ushort_t* g, ushort_t* l) {
  __builtin_amdgcn_global_load_lds(
      (const __attribute__((address_space(1))) unsigned int*)g,
      (__attribute__((address_space(3))) unsigned int*)l, 16, 0, 0);
}

// ---------------- weights fp32 -> bf16 ----------------
__global__ __launch_bounds__(256) void prep_weights(
    const float* __restrict__ qkv_w, const float* __restrict__ proj_w,
    ushort_t* __restrict__ qkvw, ushort_t* __restrict__ projw) {
  int idx = blockIdx.x * 256 + threadIdx.x;
  const int NQ = 1536 * 512;
  if (idx < NQ) {
    qkvw[idx] = f2b(qkv_w[idx]);
  } else {
    int j = idx - NQ;
    if (j < 512 * 512) projw[j] = f2b(proj_w[j]);
  }
}

// ---------------- zero fp32 buffer (1M float4 = 16MB) ----------------
__global__ __launch_bounds__(256) void zero_f4(float4* __restrict__ p) {
  p[(size_t)blockIdx.x * 256 + threadIdx.x] = float4{0.f, 0.f, 0.f, 0.f};
}

// ---------------- fp32 -> bf16 convert (8 elems/thread) ----------------
__global__ __launch_bounds__(256) void cvt_bf16(const float* __restrict__ in,
                                                ushort_t* __restrict__ out) {
  size_t i = ((size_t)blockIdx.x * 256 + threadIdx.x) * 8;
  float4 a = *(const float4*)(in + i);
  float4 b = *(const float4*)(in + i + 4);
  ushort8 u;
  u[0] = f2b(a.x); u[1] = f2b(a.y); u[2] = f2b(a.z); u[3] = f2b(a.w);
  u[4] = f2b(b.x); u[5] = f2b(b.y); u[6] = f2b(b.z); u[7] = f2b(b.w);
  *(ushort8*)(out + i) = u;
}

// ---------------- GN stats: one block per (batch, group) ----------------
__global__ __launch_bounds__(256) void gn_stats(const float* __restrict__ x,
                                                float* __restrict__ stats) {
  const int tid = threadIdx.x;
  const int bg = blockIdx.x;  // b*32+g
  const float4* xv = (const float4*)(x + (size_t)bg * 65536);
  float s = 0.f, ss = 0.f;
  for (int i = tid; i < 16384; i += 256) {
    float4 v = xv[i];
    s += v.x + v.y + v.z + v.w;
    ss += v.x * v.x + v.y * v.y + v.z * v.z + v.w * v.w;
  }
  __shared__ float red[8];
  for (int off = 32; off > 0; off >>= 1) {
    s += __shfl_down(s, off);
    ss += __shfl_down(ss, off);
  }
  if ((tid & 63) == 0) { red[tid >> 6] = s; red[4 + (tid >> 6)] = ss; }
  __syncthreads();
  if (tid == 0) {
    float st = red[0] + red[1] + red[2] + red[3];
    float sst = red[4] + red[5] + red[6] + red[7];
    float mean = st * (1.f / 65536.f);
    float var = sst * (1.f / 65536.f) - mean * mean;
    stats[bg * 2] = mean;
    stats[bg * 2 + 1] = rsqrtf(var + 1e-6f);
  }
}

// ---------------- GN apply + transpose: xnT[p][c] bf16 ----------------
__global__ __launch_bounds__(256) void gn_apply_t(
    const float* __restrict__ x, const float* __restrict__ w,
    const float* __restrict__ bgn, const float* __restrict__ stats,
    ushort_t* __restrict__ xnT) {
  __shared__ ushort_t tile[64][68];
  const int b = blockIdx.z;
  const int p0 = blockIdx.x * 64, c0 = blockIdx.y * 64;
  const int tid = threadIdx.x;
  const float* xb = x + ((size_t)b * 512 + c0) * 4096 + p0;
  const int tc = tid >> 4, tp = (tid & 15) * 4;
#pragma unroll
  for (int pass = 0; pass < 4; ++pass) {
    int c = pass * 16 + tc;
    int cg = c0 + c;
    float mean = stats[(b * 32 + (cg >> 4)) * 2];
    float inv = stats[(b * 32 + (cg >> 4)) * 2 + 1];
    float wc = w[cg] * inv;
    float bc = bgn[cg] - mean * wc;
    float4 v = *(const float4*)(xb + (size_t)c * 4096 + tp);
    tile[c][tp] = f2b(v.x * wc + bc);
    tile[c][tp + 1] = f2b(v.y * wc + bc);
    tile[c][tp + 2] = f2b(v.z * wc + bc);
    tile[c][tp + 3] = f2b(v.w * wc + bc);
  }
  __syncthreads();
  const int c8 = (tid & 7) * 8;
#pragma unroll
  for (int pass = 0; pass < 2; ++pass) {
    int p = pass * 32 + (tid >> 3);
    ushort8 u;
#pragma unroll
    for (int e = 0; e < 8; ++e) u[e] = tile[c8 + e][p];
    *(ushort8*)(xnT + ((size_t)b * 4096 + p0 + p) * 512 + c0 + c8) = u;
  }
}

// ---------------- bt-form bf16 MFMA GEMM (m97 structure) ----------------
// C[m][n] = sum_k A[m][k] * B[n][k];  ldc = N
// EPI: 0 bf16 +bias[n]; 1 bf16 +bias[m]; 2 bf16 *scale; 3 bf16; 4 f32 +bias[m]+resid
// STATS=1: additionally emit per-column (max, sumexp) partials to smp
template <int EPI, int STATS>
__global__ __launch_bounds__(256) void gemm_bt(
    const ushort_t* __restrict__ A, const ushort_t* __restrict__ B,
    void* __restrict__ Cg, const float* __restrict__ bias,
    const float* __restrict__ resid, float* __restrict__ smp, int N, int K,
    int lda, int ldb, size_t sA, size_t sB, size_t sC, float scale) {
  __shared__ __align__(16) ushort_t As[4096];  // [128][32]
  __shared__ __align__(16) ushort_t Bs[4096];
  const int bz = blockIdx.z;
  const ushort_t* Ab = A + bz * sA;
  const ushort_t* Bb = B + bz * sB;
  const int bm0 = blockIdx.y * 128, bn0 = blockIdx.x * 128;
  const int tid = threadIdx.x;
  const int w = tid >> 6, lane = tid & 63;
  const int sm = tid >> 2, sk = (tid & 3) * 8;
  const ushort_t* aS = Ab + (size_t)(bm0 + sm) * lda + sk;
  const ushort_t* bS = Bb + (size_t)(bn0 + sm) * ldb + sk;
  ushort_t* ldsA = As + w * 512;  // wave-uniform base
  ushort_t* ldsB = Bs + w * 512;
  const int wm = (w >> 1) * 64, wn = (w & 1) * 64;
  const int fr = lane & 15, fk = (lane >> 4) * 8;
  f32x4 acc[4][4] = {};
  for (int kk = 0; kk < K; kk += 32) {
    gload16(aS + kk, ldsA);
    gload16(aS + (size_t)64 * lda + kk, ldsA + 2048);
    gload16(bS + kk, ldsB);
    gload16(bS + (size_t)64 * ldb + kk, ldsB + 2048);
    __syncthreads();
    bf16x8 af[4], bfv[4];
#pragma unroll
    for (int mi = 0; mi < 4; mi++)
      af[mi] = *(const bf16x8*)&As[(wm + mi * 16 + fr) * 32 + fk];
#pragma unroll
    for (int ni = 0; ni < 4; ni++)
      bfv[ni] = *(const bf16x8*)&Bs[(wn + ni * 16 + fr) * 32 + fk];
#pragma unroll
    for (int mi = 0; mi < 4; mi++)
#pragma unroll
      for (int ni = 0; ni < 4; ni++)
        acc[mi][ni] = __builtin_amdgcn_mfma_f32_16x16x32_bf16(
            af[mi], bfv[ni], acc[mi][ni], 0, 0, 0);
    __syncthreads();
  }
  const int r0 = (lane >> 4) * 4;
  const size_t cbase = (size_t)bz * sC;
#pragma unroll
  for (int mi = 0; mi < 4; mi++) {
#pragma unroll
    for (int r = 0; r < 4; r++) {
      int gm = bm0 + wm + mi * 16 + r0 + r;
#pragma unroll
      for (int ni = 0; ni < 4; ni++) {
        int gn = bn0 + wn + ni * 16 + fr;
        float v = acc[mi][ni][r];
        size_t off = cbase + (size_t)gm * N + gn;
        if constexpr (EPI == 0) ((ushort_t*)Cg)[off] = f2b(v + bias[gn]);
        else if constexpr (EPI == 1) ((ushort_t*)Cg)[off] = f2b(v + bias[gm]);
        else if constexpr (EPI == 2) ((ushort_t*)Cg)[off] = f2b(v * scale);
        else if constexpr (EPI == 3) ((ushort_t*)Cg)[off] = f2b(v);
        else ((float*)Cg)[off] = v + bias[gm] + resid[off];
      }
    }
  }
  if constexpr (STATS) {
    // per-column (over this block's 128 rows) max & sum-exp of scaled value
    __shared__ float sredm[4][64];
    __shared__ float sreds[4][64];
    float cm[4], cs4[4];
#pragma unroll
    for (int ni = 0; ni < 4; ni++) {
      float m = -3e38f;
#pragma unroll
      for (int mi = 0; mi < 4; mi++)
#pragma unroll
        for (int r = 0; r < 4; r++) m = fmaxf(m, acc[mi][ni][r] * scale);
      m = fmaxf(m, __shfl_xor(m, 16));
      m = fmaxf(m, __shfl_xor(m, 32));
      float s = 0.f;
#pragma unroll
      for (int mi = 0; mi < 4; mi++)
#pragma unroll
        for (int r = 0; r < 4; r++)
          s += __expf(acc[mi][ni][r] * scale - m);
      s += __shfl_xor(s, 16);
      s += __shfl_xor(s, 32);
      cm[ni] = m;
      cs4[ni] = s;
    }
    if (lane < 16) {
#pragma unroll
      for (int ni = 0; ni < 4; ni++) {
        sredm[w][ni * 16 + lane] = cm[ni];
        sreds[w][ni * 16 + lane] = cs4[ni];
      }
    }
    __syncthreads();
    if (tid < 128) {
      int col = tid;
      int wa = (col < 64) ? 0 : 1, wb = wa + 2;
      int c6 = col & 63;
      float ma = sredm[wa][c6], mb = sredm[wb][c6];
      float M = fmaxf(ma, mb);
      float S = sreds[wa][c6] * __expf(ma - M) + sreds[wb][c6] * __expf(mb - M);
      size_t o = (((size_t)bz * 32 + blockIdx.y) * 4096 + bn0 + col) * 2;
      smp[o] = M;
      smp[o + 1] = S;
    }
  }
}

// ---------------- split-j PV GEMM: fp32 atomic accumulate ----------------
// OTf[b][p][c] += sum_{j in chunk} Lb'[p][j] * V[c][j]
__global__ __launch_bounds__(256) void gemm_split(
    const ushort_t* __restrict__ Lb, const ushort_t* __restrict__ Vb,
    float* __restrict__ OTf) {
  __shared__ __align__(16) ushort_t As[4096];
  __shared__ __align__(16) ushort_t Bs[4096];
  const int b = blockIdx.z >> 2, sp = blockIdx.z & 3;
  const int bm0 = blockIdx.y * 128, bn0 = blockIdx.x * 128;
  const int tid = threadIdx.x;
  const int w = tid >> 6, lane = tid & 63;
  const int sm = tid >> 2, sk = (tid & 3) * 8;
  const ushort_t* aS =
      Lb + (size_t)b * 16777216 + (size_t)(bm0 + sm) * 4096 + sp * 1024 + sk;
  const ushort_t* bS =
      Vb + (size_t)b * 2097152 + (size_t)(bn0 + sm) * 4096 + sp * 1024 + sk;
  ushort_t* ldsA = As + w * 512;
  ushort_t* ldsB = Bs + w * 512;
  const int wm = (w >> 1) * 64, wn = (w & 1) * 64;
  const int fr = lane & 15, fk = (lane >> 4) * 8;
  f32x4 acc[4][4] = {};
  for (int kk = 0; kk < 1024; kk += 32) {
    gload16(aS + kk, ldsA);
    gload16(aS + (size_t)64 * 4096 + kk, ldsA + 2048);
    gload16(bS + kk, ldsB);
    gload16(bS + (size_t)64 * 4096 + kk, ldsB + 2048);
    __syncthreads();
    bf16x8 af[4], bfv[4];
#pragma unroll
    for (int mi = 0; mi < 4; mi++)
      af[mi] = *(const bf16x8*)&As[(wm + mi * 16 + fr) * 32 + fk];
#pragma unroll
    for (int ni = 0; ni < 4; ni++)
      bfv[ni] = *(const bf16x8*)&Bs[(wn + ni * 16 + fr) * 32 + fk];
#pragma unroll
    for (int mi = 0; mi < 4; mi++)
#pragma unroll
      for (int ni = 0; ni < 4; ni++)
        acc[mi][ni] = __builtin_amdgcn_mfma_f32_16x16x32_bf16(
            af[mi], bfv[ni], acc[mi][ni], 0, 0, 0);
    __syncthreads();
  }
  const int r0 = (lane >> 4) * 4;
  float* Cb = OTf + (size_t)b * 2097152;
#pragma unroll
  for (int mi = 0; mi < 4; mi++) {
#pragma unroll
    for (int r = 0; r < 4; r++) {
      int gm = bm0 + wm + mi * 16 + r0 + r;
#pragma unroll
      for (int ni = 0; ni < 4; ni++) {
        int gn = bn0 + wn + ni * 16 + fr;
        atomicAdd(&Cb[(size_t)gm * 512 + gn], acc[mi][ni][r]);
      }
    }
  }
}

// ---------------- softmax finalize: combine 32 partials per column ----------
__global__ __launch_bounds__(256) void sm_fin(const float* __restrict__ part,
                                              float* __restrict__ cs) {
  int idx = blockIdx.x * 256 + threadIdx.x;  // b*4096 + j
  int b = idx >> 12, j = idx & 4095;
  float M = -3e38f, S = 0.f;
#pragma unroll
  for (int rc = 0; rc < 32; rc++) {
    size_t o = (((size_t)b * 32 + rc) * 4096 + j) * 2;
    float mi = part[o], si = part[o + 1];
    float nm = fmaxf(M, mi);
    S = S * __expf(M - nm) + si * __expf(mi - nm);
    M = nm;
  }
  cs[idx * 2] = M;
  cs[idx * 2 + 1] = 1.f / S;
}

__global__ __launch_bounds__(256) void sm_apply(ushort_t* __restrict__ Lb,
                                                const float* __restrict__ cs) {
  // grid (16 jblk, 32 rblk, 2 b): 256 cols x 128 rows per block
  const int tid = threadIdx.x;
  const int b = blockIdx.z;
  const int j0 = blockIdx.x * 256, r0 = blockIdx.y * 128;
  __shared__ float lm[256], lr[256];
  lm[tid] = cs[((size_t)b * 4096 + j0 + tid) * 2];
  lr[tid] = cs[((size_t)b * 4096 + j0 + tid) * 2 + 1];
  __syncthreads();
  const int jj = (tid & 31) * 8;
#pragma unroll
  for (int pass = 0; pass < 16; ++pass) {
    int r = r0 + pass * 8 + (tid >> 5);
    ushort_t* rowp = Lb + (size_t)b * 16777216 + (size_t)r * 4096 + j0 + jj;
    ushort8 u = *(ushort8*)rowp;
#pragma unroll
    for (int i = 0; i < 8; ++i)
      u[i] = f2b(__expf(b2f(u[i]) - lm[jj + i]) * lr[jj + i]);
    *(ushort8*)rowp = u;
  }
}

extern "C" void kernel_launch(void* const* d_in, const int* in_sizes, int n_in,
                              void* d_out, int out_size, void* d_ws,
                              size_t ws_size, hipStream_t stream) {
  const float* x = (const float*)d_in[0];
  const float* gn_w = (const float*)d_in[1];
  const float* gn_b = (const float*)d_in[2];
  const float* qkv_w = (const float*)d_in[3];
  const float* qkv_b = (const float*)d_in[4];
  const float* proj_w = (const float*)d_in[5];
  const float* proj_b = (const float*)d_in[6];
  float* out = (float*)d_out;

  char* ws = (char*)d_ws;
  ushort_t* xnT   = (ushort_t*)(ws);              //  8,388,608  [p][c]   (dead after V-GEMM)
  ushort_t* OT    = (ushort_t*)(ws);              //  reuses xnT region   (live from cvt)
  ushort_t* qkvw  = (ushort_t*)(ws + 8388608);    //  1,572,864
  ushort_t* projw = (ushort_t*)(ws + 9961472);    //    524,288
  float*    stats = (float*)(ws + 10485760);      //        512
  ushort_t* qkT   = (ushort_t*)(ws + 10486272);   // 16,777,216  [p][1024] (dead after GEMM2)
  float*    OTf   = (float*)(ws + 10486272);      //  reuses qkT region    (live from zero)
  ushort_t* Vb    = (ushort_t*)(ws + 27263488);   //  8,388,608  [c][p]
  ushort_t* Lb    = (ushort_t*)(ws + 35652096);   // 67,108,864  [io][j]
  float*    cs    = (float*)(ws + 102760960);     //     65,536
  float*    smp   = (float*)(ws + 102826496);     //  2,097,152  (32 partials/col)

  const float scale = 0.04419417382415922f;  // 1/sqrt(512)

  prep_weights<<<4096, 256, 0, stream>>>(qkv_w, proj_w, qkvw, projw);
  gn_stats<<<64, 256, 0, stream>>>(x, stats);
  gn_apply_t<<<dim3(64, 8, 2), 256, 0, stream>>>(x, gn_w, gn_b, stats, xnT);
  // qkT[p][o] = sum_c xnT[p][c] * qkvw[o][c] + qkv_b[o],  o in [0,1024)
  gemm_bt<0, 0><<<dim3(8, 32, 2), 256, 0, stream>>>(
      xnT, qkvw, qkT, qkv_b, nullptr, nullptr, 1024, 512, 512, 512,
      2097152, 0, 4194304, 1.f);
  // V[c][p] = sum_c' qkvw[1024+c][c'] * xnT[p][c'] + qkv_b[1024+c]
  gemm_bt<1, 0><<<dim3(32, 4, 2), 256, 0, stream>>>(
      qkvw + 524288, xnT, Vb, qkv_b + 1024, nullptr, nullptr, 4096, 512, 512,
      512, 0, 2097152, 2097152, 1.f);
  // Lb[io][j] = scale * sum_c qT[io][c] * kT[j][c]; fused per-column stats
  gemm_bt<2, 1><<<dim3(32, 32, 2), 256, 0, stream>>>(
      qkT, qkT + 512, Lb, nullptr, nullptr, smp, 4096, 512, 1024, 1024,
      4194304, 4194304, 16777216, scale);
  sm_fin<<<32, 256, 0, stream>>>(smp, cs);
  sm_apply<<<dim3(16, 32, 2), 256, 0, stream>>>(Lb, cs);
  // OTf[p][c] = sum_j P'[p][j] * V[c][j]  (split-j=4, fp32 atomics)
  zero_f4<<<4096, 256, 0, stream>>>((float4*)OTf);
  gemm_split<<<dim3(4, 32, 8), 256, 0, stream>>>(Lb, Vb, OTf);
  cvt_bf16<<<2048, 256, 0, stream>>>(OTf, OT);
  // out[o][p] = sum_c projw[o][c] * OT[p][c] + proj_b[o] + x
  gemm_bt<4, 0><<<dim3(32, 4, 2), 256, 0, stream>>>(
      projw, OT, out, proj_b, x, nullptr, 4096, 512, 512, 512,
      0, 2097152, 2097152, 1.f);
}

// Round 4
// 230.283 us; speedup vs baseline: 1.2829x; 1.2829x over previous
//
#include <hip/hip_runtime.h>
#include <hip/hip_bf16.h>
#include <math.h>

typedef unsigned short ushort_t;
typedef __attribute__((ext_vector_type(8))) unsigned short ushort8;
typedef __attribute__((ext_vector_type(4))) unsigned short ushort4_t;
typedef __attribute__((ext_vector_type(8))) __bf16 bf16x8;
typedef __attribute__((ext_vector_type(4))) float f32x4;

__device__ inline ushort_t f2b(float f) {
  __hip_bfloat16 h = __float2bfloat16(f);
  return __builtin_bit_cast(ushort_t, h);
}
__device__ inline float b2f(ushort_t u) {
  __hip_bfloat16 h = __builtin_bit_cast(__hip_bfloat16, u);
  return __bfloat162float(h);
}

__device__ inline void gload16(const ushort_t* g, ushort_t* l) {
  __builtin_amdgcn_global_load_lds(
      (const __attribute__((address_space(1))) unsigned int*)g,
      (__attribute__((address_space(3))) unsigned int*)l, 16, 0, 0);
}

// ---------------- weights fp32 -> bf16 ----------------
__global__ __launch_bounds__(256) void prep_weights(
    const float* __restrict__ qkv_w, const float* __restrict__ proj_w,
    ushort_t* __restrict__ qkvw, ushort_t* __restrict__ projw) {
  int idx = blockIdx.x * 256 + threadIdx.x;
  const int NQ = 1536 * 512;
  if (idx < NQ) {
    qkvw[idx] = f2b(qkv_w[idx]);
  } else {
    int j = idx - NQ;
    if (j < 512 * 512) projw[j] = f2b(proj_w[j]);
  }
}

// ---------------- init out = x + proj_b[o] ----------------
__global__ __launch_bounds__(256) void init_out(const float* __restrict__ x,
                                                const float* __restrict__ pb,
                                                float* __restrict__ out) {
  size_t i = ((size_t)blockIdx.x * 256 + threadIdx.x) * 8;
  int o = (int)((i >> 12) & 511);  // channel index (4096 per channel)
  float b = pb[o];
  float4 a0 = *(const float4*)(x + i);
  float4 a1 = *(const float4*)(x + i + 4);
  a0.x += b; a0.y += b; a0.z += b; a0.w += b;
  a1.x += b; a1.y += b; a1.z += b; a1.w += b;
  *(float4*)(out + i) = a0;
  *(float4*)(out + i + 4) = a1;
}

// ---------------- GN stats: one block per (batch, group) ----------------
__global__ __launch_bounds__(256) void gn_stats(const float* __restrict__ x,
                                                float* __restrict__ stats) {
  const int tid = threadIdx.x;
  const int bg = blockIdx.x;  // b*32+g
  const float4* xv = (const float4*)(x + (size_t)bg * 65536);
  float s = 0.f, ss = 0.f;
  for (int i = tid; i < 16384; i += 256) {
    float4 v = xv[i];
    s += v.x + v.y + v.z + v.w;
    ss += v.x * v.x + v.y * v.y + v.z * v.z + v.w * v.w;
  }
  __shared__ float red[8];
  for (int off = 32; off > 0; off >>= 1) {
    s += __shfl_down(s, off);
    ss += __shfl_down(ss, off);
  }
  if ((tid & 63) == 0) { red[tid >> 6] = s; red[4 + (tid >> 6)] = ss; }
  __syncthreads();
  if (tid == 0) {
    float st = red[0] + red[1] + red[2] + red[3];
    float sst = red[4] + red[5] + red[6] + red[7];
    float mean = st * (1.f / 65536.f);
    float var = sst * (1.f / 65536.f) - mean * mean;
    stats[bg * 2] = mean;
    stats[bg * 2 + 1] = rsqrtf(var + 1e-6f);
  }
}

// ---------------- GN apply + transpose: xnT[p][c] bf16 ----------------
__global__ __launch_bounds__(256) void gn_apply_t(
    const float* __restrict__ x, const float* __restrict__ w,
    const float* __restrict__ bgn, const float* __restrict__ stats,
    ushort_t* __restrict__ xnT) {
  __shared__ ushort_t tile[64][68];
  const int b = blockIdx.z;
  const int p0 = blockIdx.x * 64, c0 = blockIdx.y * 64;
  const int tid = threadIdx.x;
  const float* xb = x + ((size_t)b * 512 + c0) * 4096 + p0;
  const int tc = tid >> 4, tp = (tid & 15) * 4;
#pragma unroll
  for (int pass = 0; pass < 4; ++pass) {
    int c = pass * 16 + tc;
    int cg = c0 + c;
    float mean = stats[(b * 32 + (cg >> 4)) * 2];
    float inv = stats[(b * 32 + (cg >> 4)) * 2 + 1];
    float wc = w[cg] * inv;
    float bc = bgn[cg] - mean * wc;
    float4 v = *(const float4*)(xb + (size_t)c * 4096 + tp);
    tile[c][tp] = f2b(v.x * wc + bc);
    tile[c][tp + 1] = f2b(v.y * wc + bc);
    tile[c][tp + 2] = f2b(v.z * wc + bc);
    tile[c][tp + 3] = f2b(v.w * wc + bc);
  }
  __syncthreads();
  const int c8 = (tid & 7) * 8;
#pragma unroll
  for (int pass = 0; pass < 2; ++pass) {
    int p = pass * 32 + (tid >> 3);
    ushort8 u;
#pragma unroll
    for (int e = 0; e < 8; ++e) u[e] = tile[c8 + e][p];
    *(ushort8*)(xnT + ((size_t)b * 4096 + p0 + p) * 512 + c0 + c8) = u;
  }
}

// ------- bt-form bf16 MFMA GEMM, prefetch-double-buffered (T3 minimum) -------
// C[m][n] = sum_k A[m][k] * B[n][k];  ldc = N
// EPI: 0 bf16 +bias[n]; 2 bf16 exp(v*scale) + column stats; 3 bf16 *colsc[n];
//      4 fp32 atomicAdd into Cg
template <int EPI, int SPLIT>
__global__ __launch_bounds__(256) void gemm_bt(
    const ushort_t* __restrict__ A, const ushort_t* __restrict__ B,
    void* __restrict__ Cg, const float* __restrict__ bias,
    float* __restrict__ smp, const float* __restrict__ colsc, int N, int K,
    int lda, int ldb, size_t sA, size_t sB, size_t sC, float scale) {
  __shared__ __align__(16) ushort_t As[2][4096];  // [128][32] x2
  __shared__ __align__(16) ushort_t Bs[2][4096];
  const int bz = blockIdx.z / SPLIT, sp = blockIdx.z % SPLIT;
  const ushort_t* Ab = A + bz * sA + (size_t)sp * K;
  const ushort_t* Bb = B + bz * sB + (size_t)sp * K;
  const int bm0 = blockIdx.y * 128, bn0 = blockIdx.x * 128;
  const int tid = threadIdx.x;
  const int w = tid >> 6, lane = tid & 63;
  const int sm = tid >> 2, sk = (tid & 3) * 8;
  const ushort_t* aS = Ab + (size_t)(bm0 + sm) * lda + sk;
  const ushort_t* bS = Bb + (size_t)(bn0 + sm) * ldb + sk;
  const int wm = (w >> 1) * 64, wn = (w & 1) * 64;
  const int fr = lane & 15, fk = (lane >> 4) * 8;
  f32x4 acc[4][4] = {};

  // stage K-step kk into buffer buf
  auto stage = [&](int buf, int kk) {
    ushort_t* la = &As[buf][w * 512];
    ushort_t* lb = &Bs[buf][w * 512];
    gload16(aS + kk, la);
    gload16(aS + (size_t)64 * lda + kk, la + 2048);
    gload16(bS + kk, lb);
    gload16(bS + (size_t)64 * ldb + kk, lb + 2048);
  };

  stage(0, 0);
  __syncthreads();
  const int nt = K >> 5;
  for (int t = 0; t < nt; ++t) {
    const int cur = t & 1;
    if (t + 1 < nt) stage(cur ^ 1, (t + 1) << 5);  // prefetch BEFORE compute
    bf16x8 af[4], bfv[4];
#pragma unroll
    for (int mi = 0; mi < 4; mi++)
      af[mi] = *(const bf16x8*)&As[cur][(wm + mi * 16 + fr) * 32 + fk];
#pragma unroll
    for (int ni = 0; ni < 4; ni++)
      bfv[ni] = *(const bf16x8*)&Bs[cur][(wn + ni * 16 + fr) * 32 + fk];
#pragma unroll
    for (int mi = 0; mi < 4; mi++)
#pragma unroll
      for (int ni = 0; ni < 4; ni++)
        acc[mi][ni] = __builtin_amdgcn_mfma_f32_16x16x32_bf16(
            af[mi], bfv[ni], acc[mi][ni], 0, 0, 0);
    __syncthreads();  // drains prefetch vmcnt + all waves done with buf[cur]
  }

  const int r0 = (lane >> 4) * 4;
  const size_t cbase = (size_t)bz * sC;
#pragma unroll
  for (int mi = 0; mi < 4; mi++) {
#pragma unroll
    for (int r = 0; r < 4; r++) {
      int gm = bm0 + wm + mi * 16 + r0 + r;
#pragma unroll
      for (int ni = 0; ni < 4; ni++) {
        int gn = bn0 + wn + ni * 16 + fr;
        float v = acc[mi][ni][r];
        size_t off = cbase + (size_t)gm * N + gn;
        if constexpr (EPI == 0) {
          ((ushort_t*)Cg)[off] = f2b(v + bias[gn]);
        } else if constexpr (EPI == 2) {
          ((ushort_t*)Cg)[off] = f2b(__expf(fminf(v * scale, 80.f)));
        } else if constexpr (EPI == 3) {
          ((ushort_t*)Cg)[off] = f2b(v * colsc[(size_t)bz * 4096 + gn]);
        } else {
          atomicAdd(&((float*)Cg)[off], v);
        }
      }
    }
  }

  if constexpr (EPI == 2) {
    // per-column (over this block's 128 rows) max & sum-exp of scaled value
    __shared__ float sredm[4][64];
    __shared__ float sreds[4][64];
    float cm[4], cs4[4];
#pragma unroll
    for (int ni = 0; ni < 4; ni++) {
      float m = -3e38f;
#pragma unroll
      for (int mi = 0; mi < 4; mi++)
#pragma unroll
        for (int r = 0; r < 4; r++) m = fmaxf(m, acc[mi][ni][r] * scale);
      m = fmaxf(m, __shfl_xor(m, 16));
      m = fmaxf(m, __shfl_xor(m, 32));
      float s = 0.f;
#pragma unroll
      for (int mi = 0; mi < 4; mi++)
#pragma unroll
        for (int r = 0; r < 4; r++)
          s += __expf(acc[mi][ni][r] * scale - m);
      s += __shfl_xor(s, 16);
      s += __shfl_xor(s, 32);
      cm[ni] = m;
      cs4[ni] = s;
    }
    __syncthreads();
    if (lane < 16) {
#pragma unroll
      for (int ni = 0; ni < 4; ni++) {
        sredm[w][ni * 16 + lane] = cm[ni];
        sreds[w][ni * 16 + lane] = cs4[ni];
      }
    }
    __syncthreads();
    if (tid < 128) {
      int col = tid;
      int wa = (col < 64) ? 0 : 1, wb = wa + 2;
      int c6 = col & 63;
      float ma = sredm[wa][c6], mb = sredm[wb][c6];
      float M = fmaxf(ma, mb);
      float S = sreds[wa][c6] * __expf(ma - M) + sreds[wb][c6] * __expf(mb - M);
      size_t o = (((size_t)bz * 32 + blockIdx.y) * 4096 + bn0 + col) * 2;
      smp[o] = M;
      smp[o + 1] = S;
    }
  }
}

// -------- softmax finalize: alpha_j = exp(-M_j)/S_j from 32 partials --------
__global__ __launch_bounds__(256) void sm_fin(const float* __restrict__ part,
                                              float* __restrict__ alpha) {
  int idx = blockIdx.x * 256 + threadIdx.x;  // b*4096 + j
  int b = idx >> 12, j = idx & 4095;
  float M = -3e38f, S = 0.f;
#pragma unroll
  for (int rc = 0; rc < 32; rc++) {
    size_t o = (((size_t)b * 32 + rc) * 4096 + j) * 2;
    float mi = part[o], si = part[o + 1];
    float nm = fmaxf(M, mi);
    S = S * __expf(M - nm) + si * __expf(mi - nm);
    M = nm;
  }
  alpha[idx] = __expf(-M) / S;
}

extern "C" void kernel_launch(void* const* d_in, const int* in_sizes, int n_in,
                              void* d_out, int out_size, void* d_ws,
                              size_t ws_size, hipStream_t stream) {
  const float* x = (const float*)d_in[0];
  const float* gn_w = (const float*)d_in[1];
  const float* gn_b = (const float*)d_in[2];
  const float* qkv_w = (const float*)d_in[3];
  const float* qkv_b = (const float*)d_in[4];
  const float* proj_w = (const float*)d_in[5];
  const float* proj_b = (const float*)d_in[6];
  float* out = (float*)d_out;

  char* ws = (char*)d_ws;
  ushort_t* xnT   = (ushort_t*)(ws);              //  8,388,608  [p][c] (dead after QKV)
  ushort_t* Wpp   = (ushort_t*)(ws);              //  reuse: W''[o][j] 8,388,608
  ushort_t* qkvw  = (ushort_t*)(ws + 8388608);    //  1,572,864
  ushort_t* projw = (ushort_t*)(ws + 9961472);    //    524,288
  float*    stats = (float*)(ws + 10485760);      //        512
  ushort_t* qkvT  = (ushort_t*)(ws + 10486272);   // 25,165,824  [p][1536] (q|k|v)
  ushort_t* P     = (ushort_t*)(ws + 35652096);   // 67,108,864  [p][j] = exp(L)
  float*    smp   = (float*)(ws + 102760960);     //  2,097,152  (32 partials/col)
  float*    alpha = (float*)(ws + 104858112);     //     32,768

  const float scale = 0.04419417382415922f;  // 1/sqrt(512)
  const size_t sXN = 2097152, sQKV = (size_t)4096 * 1536, sP = 16777216;

  prep_weights<<<4096, 256, 0, stream>>>(qkv_w, proj_w, qkvw, projw);
  gn_stats<<<64, 256, 0, stream>>>(x, stats);
  gn_apply_t<<<dim3(64, 8, 2), 256, 0, stream>>>(x, gn_w, gn_b, stats, xnT);
  init_out<<<2048, 256, 0, stream>>>(x, proj_b, out);
  // qkvT[p][o] = sum_c xnT[p][c]*qkvw[o][c] + qkv_b[o], o in [0,1536)
  gemm_bt<0, 1><<<dim3(12, 32, 2), 256, 0, stream>>>(
      xnT, qkvw, qkvT, qkv_b, nullptr, nullptr, 1536, 512, 512, 512,
      sXN, 0, sQKV, 1.f);
  // P[io][j] = exp(scale * sum_c qT[io][c]*kT[j][c]) ; fused column stats
  gemm_bt<2, 1><<<dim3(32, 32, 2), 256, 0, stream>>>(
      qkvT, qkvT + 512, P, nullptr, smp, nullptr, 4096, 512, 1536, 1536,
      sQKV, sQKV, sP, scale);
  sm_fin<<<32, 256, 0, stream>>>(smp, alpha);
  // W''[o][j] = alpha_j * sum_c projw[o][c]*vT[j][c]
  gemm_bt<3, 1><<<dim3(32, 4, 2), 256, 0, stream>>>(
      projw, qkvT + 1024, Wpp, nullptr, nullptr, alpha, 4096, 512, 512, 1536,
      0, sQKV, sXN, 1.f);
  // out[o][p] += sum_j W''[o][j]*P[p][j]   (split-j=4, fp32 atomics)
  gemm_bt<4, 4><<<dim3(32, 4, 8), 256, 0, stream>>>(
      Wpp, P, out, nullptr, nullptr, nullptr, 4096, 1024, 4096, 4096,
      sXN, sP, sXN, 1.f);
}

// Round 5
// 216.622 us; speedup vs baseline: 1.3638x; 1.0631x over previous
//
#include <hip/hip_runtime.h>
#include <hip/hip_bf16.h>
#include <math.h>

typedef unsigned short ushort_t;
typedef __attribute__((ext_vector_type(8))) unsigned short ushort8;
typedef __attribute__((ext_vector_type(4))) unsigned short ushort4_t;
typedef __attribute__((ext_vector_type(8))) __bf16 bf16x8;
typedef __attribute__((ext_vector_type(4))) float f32x4;

__device__ inline ushort_t f2b(float f) {
  __hip_bfloat16 h = __float2bfloat16(f);
  return __builtin_bit_cast(ushort_t, h);
}
__device__ inline float b2f(ushort_t u) {
  __hip_bfloat16 h = __builtin_bit_cast(__hip_bfloat16, u);
  return __bfloat162float(h);
}

__device__ inline void gload16(const ushort_t* g, ushort_t* l) {
  __builtin_amdgcn_global_load_lds(
      (const __attribute__((address_space(1))) unsigned int*)g,
      (__attribute__((address_space(3))) unsigned int*)l, 16, 0, 0);
}

// ---------------- weights fp32 -> bf16 ----------------
__global__ __launch_bounds__(256) void prep_weights(
    const float* __restrict__ qkv_w, const float* __restrict__ proj_w,
    ushort_t* __restrict__ qkvw, ushort_t* __restrict__ projw) {
  int idx = blockIdx.x * 256 + threadIdx.x;
  const int NQ = 1536 * 512;
  if (idx < NQ) {
    qkvw[idx] = f2b(qkv_w[idx]);
  } else {
    int j = idx - NQ;
    if (j < 512 * 512) projw[j] = f2b(proj_w[j]);
  }
}

// ---------------- init out = x + proj_b[o] ----------------
__global__ __launch_bounds__(256) void init_out(const float* __restrict__ x,
                                                const float* __restrict__ pb,
                                                float* __restrict__ out) {
  size_t i = ((size_t)blockIdx.x * 256 + threadIdx.x) * 8;
  int o = (int)((i >> 12) & 511);
  float b = pb[o];
  float4 a0 = *(const float4*)(x + i);
  float4 a1 = *(const float4*)(x + i + 4);
  a0.x += b; a0.y += b; a0.z += b; a0.w += b;
  a1.x += b; a1.y += b; a1.z += b; a1.w += b;
  *(float4*)(out + i) = a0;
  *(float4*)(out + i + 4) = a1;
}

// ---------------- GN stats ----------------
__global__ __launch_bounds__(256) void gn_stats(const float* __restrict__ x,
                                                float* __restrict__ stats) {
  const int tid = threadIdx.x;
  const int bg = blockIdx.x;
  const float4* xv = (const float4*)(x + (size_t)bg * 65536);
  float s = 0.f, ss = 0.f;
  for (int i = tid; i < 16384; i += 256) {
    float4 v = xv[i];
    s += v.x + v.y + v.z + v.w;
    ss += v.x * v.x + v.y * v.y + v.z * v.z + v.w * v.w;
  }
  __shared__ float red[8];
  for (int off = 32; off > 0; off >>= 1) {
    s += __shfl_down(s, off);
    ss += __shfl_down(ss, off);
  }
  if ((tid & 63) == 0) { red[tid >> 6] = s; red[4 + (tid >> 6)] = ss; }
  __syncthreads();
  if (tid == 0) {
    float st = red[0] + red[1] + red[2] + red[3];
    float sst = red[4] + red[5] + red[6] + red[7];
    float mean = st * (1.f / 65536.f);
    float var = sst * (1.f / 65536.f) - mean * mean;
    stats[bg * 2] = mean;
    stats[bg * 2 + 1] = rsqrtf(var + 1e-6f);
  }
}

// ---------------- GN apply + transpose ----------------
__global__ __launch_bounds__(256) void gn_apply_t(
    const float* __restrict__ x, const float* __restrict__ w,
    const float* __restrict__ bgn, const float* __restrict__ stats,
    ushort_t* __restrict__ xnT) {
  __shared__ ushort_t tile[64][68];
  const int b = blockIdx.z;
  const int p0 = blockIdx.x * 64, c0 = blockIdx.y * 64;
  const int tid = threadIdx.x;
  const float* xb = x + ((size_t)b * 512 + c0) * 4096 + p0;
  const int tc = tid >> 4, tp = (tid & 15) * 4;
#pragma unroll
  for (int pass = 0; pass < 4; ++pass) {
    int c = pass * 16 + tc;
    int cg = c0 + c;
    float mean = stats[(b * 32 + (cg >> 4)) * 2];
    float inv = stats[(b * 32 + (cg >> 4)) * 2 + 1];
    float wc = w[cg] * inv;
    float bc = bgn[cg] - mean * wc;
    float4 v = *(const float4*)(xb + (size_t)c * 4096 + tp);
    tile[c][tp] = f2b(v.x * wc + bc);
    tile[c][tp + 1] = f2b(v.y * wc + bc);
    tile[c][tp + 2] = f2b(v.z * wc + bc);
    tile[c][tp + 3] = f2b(v.w * wc + bc);
  }
  __syncthreads();
  const int c8 = (tid & 7) * 8;
#pragma unroll
  for (int pass = 0; pass < 2; ++pass) {
    int p = pass * 32 + (tid >> 3);
    ushort8 u;
#pragma unroll
    for (int e = 0; e < 8; ++e) u[e] = tile[c8 + e][p];
    *(ushort8*)(xnT + ((size_t)b * 4096 + p0 + p) * 512 + c0 + c8) = u;
  }
}

// ====== 256x256 8-phase bf16 GEMM (T2+T3+T4+T5), bt-form ======
// C[m][n] = sum_k A[m][k]*B[n][k]
// EPI: 0 bf16 +bias[n]; 2 bf16 exp(v*scale) + column stats; 4 fp32 atomicAdd
template <int EPI, int SPLIT>
__global__ __launch_bounds__(512, 2) void gemm8(
    const ushort_t* __restrict__ A, const ushort_t* __restrict__ B,
    void* __restrict__ Cg, const float* __restrict__ bias,
    float* __restrict__ smp, int N, int K, int lda, int ldb, size_t sA,
    size_t sB, size_t sC, float scale) {
  __shared__ __align__(16) ushort_t Al[2][256 * 64];  // 32KB x2
  __shared__ __align__(16) ushort_t Bl[2][256 * 64];  // 32KB x2
  __shared__ float s_max[2][256], s_sum[2][256];

  const int bz = blockIdx.z / SPLIT, sp = blockIdx.z % SPLIT;
  const ushort_t* Ab = A + bz * sA + (size_t)sp * K;
  const ushort_t* Bb = B + bz * sB + (size_t)sp * K;
  const int bm0 = blockIdx.y * 256, bn0 = blockIdx.x * 256;
  const int tid = threadIdx.x;
  const int w = tid >> 6, lane = tid & 63;
  const int wr = w >> 2, wc = w & 3;  // wave tile: rows wr*128, cols wc*64
  const int fr = lane & 15, fq = lane >> 4;

  // staging mapping: per gload, thread tid covers LDS 16B-block tid of a
  // 64-row group; LDS is linear, global source is inverse-swizzled.
  const int srow = tid >> 3, scb = tid & 7;
  const int ssw = scb ^ (srow & 7);
  const ushort_t* aS = Ab + (size_t)(bm0 + srow) * lda + ssw * 8;
  const ushort_t* bS = Bb + (size_t)(bn0 + srow) * ldb + ssw * 8;

  auto stage_a = [&](int s, int kk) {
#pragma unroll
    for (int g = 0; g < 4; ++g)
      gload16(aS + (size_t)(g * 64) * lda + kk, &Al[s][g * 4096 + w * 512]);
  };
  auto stage_b = [&](int s, int kk) {
#pragma unroll
    for (int g = 0; g < 4; ++g)
      gload16(bS + (size_t)(g * 64) * ldb + kk, &Bl[s][g * 4096 + w * 512]);
  };

  f32x4 acc[8][4] = {};
  bf16x8 a_r[4][2], b_r[4][2];

  auto read_a = [&](int s, int mh) {
#pragma unroll
    for (int mi = 0; mi < 4; ++mi) {
      int row = wr * 128 + mh * 64 + mi * 16 + fr;
#pragma unroll
      for (int ks = 0; ks < 2; ++ks) {
        int blk = ((ks * 4 + fq) ^ (row & 7)) * 8;
        a_r[mi][ks] = *(const bf16x8*)&Al[s][row * 64 + blk];
      }
    }
  };
  auto read_b = [&](int s, int nh) {
#pragma unroll
    for (int ni = 0; ni < 2; ++ni) {
      int row = wc * 64 + nh * 32 + ni * 16 + fr;
#pragma unroll
      for (int ks = 0; ks < 2; ++ks) {
        int blk = ((ks * 4 + fq) ^ (row & 7)) * 8;
        b_r[nh * 2 + ni][ks] = *(const bf16x8*)&Bl[s][row * 64 + blk];
      }
    }
  };
  auto phase_mfma = [&](int mh, int nh) {
    __builtin_amdgcn_s_setprio(1);
#pragma unroll
    for (int ks = 0; ks < 2; ++ks)
#pragma unroll
      for (int mi = 0; mi < 4; ++mi)
#pragma unroll
        for (int ni = 0; ni < 2; ++ni)
          acc[mh * 4 + mi][nh * 2 + ni] =
              __builtin_amdgcn_mfma_f32_16x16x32_bf16(
                  a_r[mi][ks], b_r[nh * 2 + ni][ks],
                  acc[mh * 4 + mi][nh * 2 + ni], 0, 0, 0);
    __builtin_amdgcn_s_setprio(0);
  };

  const int nt = K >> 6;
  // prologue: stage tiles 0 and 1; gate tile 0 landed (8 newest = tile 1)
  stage_b(0, 0);
  stage_a(0, 0);
  if (nt > 1) {
    stage_b(1, 64);
    stage_a(1, 64);
    asm volatile("s_waitcnt vmcnt(8)" ::: "memory");
  } else {
    asm volatile("s_waitcnt vmcnt(0)" ::: "memory");
  }
  __builtin_amdgcn_s_barrier();

  for (int t = 0; t < nt; ++t) {
    const int s = t & 1;
    const int kk2 = (t + 2) << 6;
    const bool st2 = (t + 2) < nt;
    // P1: read A-half0 + B-half0 of tile t
    read_a(s, 0);
    read_b(s, 0);
    __builtin_amdgcn_s_barrier();
    phase_mfma(0, 0);
    __builtin_amdgcn_s_barrier();
    // P2: read B-half1
    read_b(s, 1);
    __builtin_amdgcn_s_barrier();
    phase_mfma(0, 1);
    __builtin_amdgcn_s_barrier();
    // P3: read A-half1; stage tile t+2's B into slot s (B[s] free after P2)
    read_a(s, 1);
    asm volatile("" ::: "memory");
    if (st2) stage_b(s, kk2);
    __builtin_amdgcn_s_barrier();
    phase_mfma(1, 0);
    __builtin_amdgcn_s_barrier();
    // P4: stage tile t+2's A into slot s (A[s] free after P3); gate t+1
    asm volatile("" ::: "memory");
    if (st2) stage_a(s, kk2);
    __builtin_amdgcn_s_barrier();
    phase_mfma(1, 1);
    if (st2)
      asm volatile("s_waitcnt vmcnt(8)" ::: "memory");
    else if (t + 1 < nt)
      asm volatile("s_waitcnt vmcnt(0)" ::: "memory");
    __builtin_amdgcn_s_barrier();
  }

  // epilogue
  const size_t cbase = (size_t)bz * sC;
#pragma unroll
  for (int mi = 0; mi < 8; ++mi) {
#pragma unroll
    for (int r = 0; r < 4; ++r) {
      int gm = bm0 + wr * 128 + mi * 16 + fq * 4 + r;
#pragma unroll
      for (int ni = 0; ni < 4; ++ni) {
        int gn = bn0 + wc * 64 + ni * 16 + fr;
        float v = acc[mi][ni][r];
        size_t off = cbase + (size_t)gm * N + gn;
        if constexpr (EPI == 0) {
          ((ushort_t*)Cg)[off] = f2b(v + bias[gn]);
        } else if constexpr (EPI == 2) {
          ((ushort_t*)Cg)[off] = f2b(__expf(fminf(v * scale, 80.f)));
        } else {
          atomicAdd(&((float*)Cg)[off], v);
        }
      }
    }
  }

  if constexpr (EPI == 2) {
    // per-column stats over this block's 256 rows
    float cm[4], cs4[4];
#pragma unroll
    for (int ni = 0; ni < 4; ++ni) {
      float m = -3e38f;
#pragma unroll
      for (int mi = 0; mi < 8; ++mi)
#pragma unroll
        for (int r = 0; r < 4; ++r) m = fmaxf(m, acc[mi][ni][r] * scale);
      m = fmaxf(m, __shfl_xor(m, 16));
      m = fmaxf(m, __shfl_xor(m, 32));
      float s = 0.f;
#pragma unroll
      for (int mi = 0; mi < 8; ++mi)
#pragma unroll
        for (int r = 0; r < 4; ++r) s += __expf(acc[mi][ni][r] * scale - m);
      s += __shfl_xor(s, 16);
      s += __shfl_xor(s, 32);
      cm[ni] = m;
      cs4[ni] = s;
    }
    __syncthreads();
    if (lane < 16) {
#pragma unroll
      for (int ni = 0; ni < 4; ++ni) {
        s_max[wr][wc * 64 + ni * 16 + lane] = cm[ni];
        s_sum[wr][wc * 64 + ni * 16 + lane] = cs4[ni];
      }
    }
    __syncthreads();
    if (tid < 256) {
      float m0 = s_max[0][tid], m1 = s_max[1][tid];
      float M = fmaxf(m0, m1);
      float S = s_sum[0][tid] * __expf(m0 - M) + s_sum[1][tid] * __expf(m1 - M);
      size_t o = (((size_t)bz * 16 + blockIdx.y) * 4096 + bn0 + tid) * 2;
      smp[o] = M;
      smp[o + 1] = S;
    }
  }
}

// ------- 128x128 dbuf GEMM (kept for the small W'' GEMM) -------
// EPI: 3 bf16 *colsc[n]
template <int EPI, int SPLIT>
__global__ __launch_bounds__(256) void gemm_bt(
    const ushort_t* __restrict__ A, const ushort_t* __restrict__ B,
    void* __restrict__ Cg, const float* __restrict__ bias,
    float* __restrict__ smp, const float* __restrict__ colsc, int N, int K,
    int lda, int ldb, size_t sA, size_t sB, size_t sC, float scale) {
  __shared__ __align__(16) ushort_t As[2][4096];
  __shared__ __align__(16) ushort_t Bs[2][4096];
  const int bz = blockIdx.z / SPLIT, sp = blockIdx.z % SPLIT;
  const ushort_t* Ab = A + bz * sA + (size_t)sp * K;
  const ushort_t* Bb = B + bz * sB + (size_t)sp * K;
  const int bm0 = blockIdx.y * 128, bn0 = blockIdx.x * 128;
  const int tid = threadIdx.x;
  const int w = tid >> 6, lane = tid & 63;
  const int sm = tid >> 2, sk = (tid & 3) * 8;
  const ushort_t* aS = Ab + (size_t)(bm0 + sm) * lda + sk;
  const ushort_t* bS = Bb + (size_t)(bn0 + sm) * ldb + sk;
  const int wm = (w >> 1) * 64, wn = (w & 1) * 64;
  const int fr = lane & 15, fk = (lane >> 4) * 8;
  f32x4 acc[4][4] = {};

  auto stage = [&](int buf, int kk) {
    ushort_t* la = &As[buf][w * 512];
    ushort_t* lb = &Bs[buf][w * 512];
    gload16(aS + kk, la);
    gload16(aS + (size_t)64 * lda + kk, la + 2048);
    gload16(bS + kk, lb);
    gload16(bS + (size_t)64 * ldb + kk, lb + 2048);
  };

  stage(0, 0);
  __syncthreads();
  const int nt = K >> 5;
  for (int t = 0; t < nt; ++t) {
    const int cur = t & 1;
    if (t + 1 < nt) stage(cur ^ 1, (t + 1) << 5);
    bf16x8 af[4], bfv[4];
#pragma unroll
    for (int mi = 0; mi < 4; mi++)
      af[mi] = *(const bf16x8*)&As[cur][(wm + mi * 16 + fr) * 32 + fk];
#pragma unroll
    for (int ni = 0; ni < 4; ni++)
      bfv[ni] = *(const bf16x8*)&Bs[cur][(wn + ni * 16 + fr) * 32 + fk];
#pragma unroll
    for (int mi = 0; mi < 4; mi++)
#pragma unroll
      for (int ni = 0; ni < 4; ni++)
        acc[mi][ni] = __builtin_amdgcn_mfma_f32_16x16x32_bf16(
            af[mi], bfv[ni], acc[mi][ni], 0, 0, 0);
    __syncthreads();
  }

  const int r0 = (lane >> 4) * 4;
  const size_t cbase = (size_t)bz * sC;
#pragma unroll
  for (int mi = 0; mi < 4; mi++) {
#pragma unroll
    for (int r = 0; r < 4; r++) {
      int gm = bm0 + wm + mi * 16 + r0 + r;
#pragma unroll
      for (int ni = 0; ni < 4; ni++) {
        int gn = bn0 + wn + ni * 16 + fr;
        float v = acc[mi][ni][r];
        size_t off = cbase + (size_t)gm * N + gn;
        if constexpr (EPI == 3) {
          ((ushort_t*)Cg)[off] = f2b(v * colsc[(size_t)bz * 4096 + gn]);
        }
      }
    }
  }
}

// -------- softmax finalize: alpha_j = exp(-M_j)/S_j from 16 partials --------
__global__ __launch_bounds__(256) void sm_fin(const float* __restrict__ part,
                                              float* __restrict__ alpha) {
  int idx = blockIdx.x * 256 + threadIdx.x;  // b*4096 + j
  int b = idx >> 12, j = idx & 4095;
  float M = -3e38f, S = 0.f;
#pragma unroll
  for (int rc = 0; rc < 16; rc++) {
    size_t o = (((size_t)b * 16 + rc) * 4096 + j) * 2;
    float mi = part[o], si = part[o + 1];
    float nm = fmaxf(M, mi);
    S = S * __expf(M - nm) + si * __expf(mi - nm);
    M = nm;
  }
  alpha[idx] = __expf(-M) / S;
}

extern "C" void kernel_launch(void* const* d_in, const int* in_sizes, int n_in,
                              void* d_out, int out_size, void* d_ws,
                              size_t ws_size, hipStream_t stream) {
  const float* x = (const float*)d_in[0];
  const float* gn_w = (const float*)d_in[1];
  const float* gn_b = (const float*)d_in[2];
  const float* qkv_w = (const float*)d_in[3];
  const float* qkv_b = (const float*)d_in[4];
  const float* proj_w = (const float*)d_in[5];
  const float* proj_b = (const float*)d_in[6];
  float* out = (float*)d_out;

  char* ws = (char*)d_ws;
  ushort_t* xnT   = (ushort_t*)(ws);              //  8 MB [p][c] (dead after QKV)
  ushort_t* Wpp   = (ushort_t*)(ws);              //  reuse: W''[b][o][j] 16MB? no: 8MB (2 batches x 4MB)
  ushort_t* qkvw  = (ushort_t*)(ws + 8388608);
  ushort_t* projw = (ushort_t*)(ws + 9961472);
  float*    stats = (float*)(ws + 10485760);
  ushort_t* qkvT  = (ushort_t*)(ws + 10486272);   // 25,165,824  [p][1536]
  ushort_t* P     = (ushort_t*)(ws + 35652096);   // 67,108,864  [p][j] = exp(L)
  float*    smp   = (float*)(ws + 102760960);     //  1 MB (16 partials/col)
  float*    alpha = (float*)(ws + 104858112);     //  32 KB

  const float scale = 0.04419417382415922f;  // 1/sqrt(512)
  const size_t sXN = 2097152, sQKV = (size_t)4096 * 1536, sP = 16777216;

  prep_weights<<<4096, 256, 0, stream>>>(qkv_w, proj_w, qkvw, projw);
  gn_stats<<<64, 256, 0, stream>>>(x, stats);
  gn_apply_t<<<dim3(64, 8, 2), 256, 0, stream>>>(x, gn_w, gn_b, stats, xnT);
  init_out<<<2048, 256, 0, stream>>>(x, proj_b, out);
  // qkvT[p][o] = sum_c xnT[p][c]*qkvw[o][c] + qkv_b[o]  (M=8192 both batches)
  gemm8<0, 1><<<dim3(6, 32, 1), 512, 0, stream>>>(
      xnT, qkvw, qkvT, qkv_b, nullptr, 1536, 512, 512, 512, 0, 0, 0, 1.f);
  // P[io][j] = exp(scale * qT[io].kT[j]) ; fused column stats (16 chunks)
  gemm8<2, 1><<<dim3(16, 16, 2), 512, 0, stream>>>(
      qkvT, qkvT + 512, P, nullptr, smp, 4096, 512, 1536, 1536, sQKV, sQKV,
      sP, scale);
  sm_fin<<<32, 256, 0, stream>>>(smp, alpha);
  // W''[o][j] = alpha_j * sum_c projw[o][c]*vT[j][c]
  gemm_bt<3, 1><<<dim3(32, 4, 2), 256, 0, stream>>>(
      projw, qkvT + 1024, Wpp, nullptr, nullptr, alpha, 4096, 512, 512, 1536,
      0, sQKV, sXN, 1.f);
  // out[o][p] += sum_j W''[o][j]*P[p][j]  (split-j=4, fp32 atomics)
  gemm8<4, 4><<<dim3(16, 2, 8), 512, 0, stream>>>(
      Wpp, P, out, nullptr, nullptr, 4096, 1024, 4096, 4096, sXN, sP, sXN,
      1.f);
}

// Round 6
// 214.437 us; speedup vs baseline: 1.3776x; 1.0102x over previous
//
#include <hip/hip_runtime.h>
#include <hip/hip_bf16.h>
#include <math.h>

typedef unsigned short ushort_t;
typedef __attribute__((ext_vector_type(8))) unsigned short ushort8;
typedef __attribute__((ext_vector_type(4))) unsigned short ushort4_t;
typedef __attribute__((ext_vector_type(8))) __bf16 bf16x8;
typedef __attribute__((ext_vector_type(4))) float f32x4;

__device__ inline ushort_t f2b(float f) {
  __hip_bfloat16 h = __float2bfloat16(f);
  return __builtin_bit_cast(ushort_t, h);
}
__device__ inline float b2f(ushort_t u) {
  __hip_bfloat16 h = __builtin_bit_cast(__hip_bfloat16, u);
  return __bfloat162float(h);
}

__device__ inline void gload16(const ushort_t* g, ushort_t* l) {
  __builtin_amdgcn_global_load_lds(
      (const __attribute__((address_space(1))) unsigned int*)g,
      (__attribute__((address_space(3))) unsigned int*)l, 16, 0, 0);
}

// bijective XCD swizzle (m204): chunk of consecutive work-ids -> one XCD,
// work-id ordered x-fastest so same-A-panel blocks share an XCD's L2.
__device__ inline void xcd_swz(int& bx, int& by, int& bz) {
  const int nx = gridDim.x, ny = gridDim.y;
  const int nwg = nx * ny * gridDim.z;
  const int orig = blockIdx.x + nx * (blockIdx.y + ny * blockIdx.z);
  const int q = nwg >> 3, r = nwg & 7, xcd = orig & 7, loc = orig >> 3;
  const int wg = (xcd < r ? xcd * (q + 1) : r * (q + 1) + (xcd - r) * q) + loc;
  bx = wg % nx;
  by = (wg / nx) % ny;
  bz = wg / (nx * ny);
}

// ---------------- weights fp32 -> bf16 ----------------
__global__ __launch_bounds__(256) void prep_weights(
    const float* __restrict__ qkv_w, const float* __restrict__ proj_w,
    ushort_t* __restrict__ qkvw, ushort_t* __restrict__ projw) {
  int idx = blockIdx.x * 256 + threadIdx.x;
  const int NQ = 1536 * 512;
  if (idx < NQ) {
    qkvw[idx] = f2b(qkv_w[idx]);
  } else {
    int j = idx - NQ;
    if (j < 512 * 512) projw[j] = f2b(proj_w[j]);
  }
}

// ---------------- GN stats ----------------
__global__ __launch_bounds__(256) void gn_stats(const float* __restrict__ x,
                                                float* __restrict__ stats) {
  const int tid = threadIdx.x;
  const int bg = blockIdx.x;
  const float4* xv = (const float4*)(x + (size_t)bg * 65536);
  float s = 0.f, ss = 0.f;
  for (int i = tid; i < 16384; i += 256) {
    float4 v = xv[i];
    s += v.x + v.y + v.z + v.w;
    ss += v.x * v.x + v.y * v.y + v.z * v.z + v.w * v.w;
  }
  __shared__ float red[8];
  for (int off = 32; off > 0; off >>= 1) {
    s += __shfl_down(s, off);
    ss += __shfl_down(ss, off);
  }
  if ((tid & 63) == 0) { red[tid >> 6] = s; red[4 + (tid >> 6)] = ss; }
  __syncthreads();
  if (tid == 0) {
    float st = red[0] + red[1] + red[2] + red[3];
    float sst = red[4] + red[5] + red[6] + red[7];
    float mean = st * (1.f / 65536.f);
    float var = sst * (1.f / 65536.f) - mean * mean;
    stats[bg * 2] = mean;
    stats[bg * 2 + 1] = rsqrtf(var + 1e-6f);
  }
}

// ---------------- GN apply + transpose ----------------
__global__ __launch_bounds__(256) void gn_apply_t(
    const float* __restrict__ x, const float* __restrict__ w,
    const float* __restrict__ bgn, const float* __restrict__ stats,
    ushort_t* __restrict__ xnT) {
  __shared__ ushort_t tile[64][68];
  const int b = blockIdx.z;
  const int p0 = blockIdx.x * 64, c0 = blockIdx.y * 64;
  const int tid = threadIdx.x;
  const float* xb = x + ((size_t)b * 512 + c0) * 4096 + p0;
  const int tc = tid >> 4, tp = (tid & 15) * 4;
#pragma unroll
  for (int pass = 0; pass < 4; ++pass) {
    int c = pass * 16 + tc;
    int cg = c0 + c;
    float mean = stats[(b * 32 + (cg >> 4)) * 2];
    float inv = stats[(b * 32 + (cg >> 4)) * 2 + 1];
    float wc = w[cg] * inv;
    float bc = bgn[cg] - mean * wc;
    float4 v = *(const float4*)(xb + (size_t)c * 4096 + tp);
    tile[c][tp] = f2b(v.x * wc + bc);
    tile[c][tp + 1] = f2b(v.y * wc + bc);
    tile[c][tp + 2] = f2b(v.z * wc + bc);
    tile[c][tp + 3] = f2b(v.w * wc + bc);
  }
  __syncthreads();
  const int c8 = (tid & 7) * 8;
#pragma unroll
  for (int pass = 0; pass < 2; ++pass) {
    int p = pass * 32 + (tid >> 3);
    ushort8 u;
#pragma unroll
    for (int e = 0; e < 8; ++e) u[e] = tile[c8 + e][p];
    *(ushort8*)(xnT + ((size_t)b * 4096 + p0 + p) * 512 + c0 + c8) = u;
  }
}

// ====== 256x256 8-phase bf16 GEMM, bt-form, XCD-swizzled ======
// EPI: 0 bf16 +bias[n]; 2 bf16 exp(v*scale) + column stats
template <int EPI>
__global__ __launch_bounds__(512, 2) void gemm8(
    const ushort_t* __restrict__ A, const ushort_t* __restrict__ B,
    void* __restrict__ Cg, const float* __restrict__ bias,
    float* __restrict__ smp, int N, int K, int lda, int ldb, size_t sA,
    size_t sB, size_t sC, float scale) {
  __shared__ __align__(16) ushort_t Al[2][256 * 64];
  __shared__ __align__(16) ushort_t Bl[2][256 * 64];
  __shared__ float s_max[2][256], s_sum[2][256];

  int bx, by, bz;
  xcd_swz(bx, by, bz);
  const ushort_t* Ab = A + bz * sA;
  const ushort_t* Bb = B + bz * sB;
  const int bm0 = by * 256, bn0 = bx * 256;
  const int tid = threadIdx.x;
  const int w = tid >> 6, lane = tid & 63;
  const int wr = w >> 2, wc = w & 3;
  const int fr = lane & 15, fq = lane >> 4;

  const int srow = tid >> 3, scb = tid & 7;
  const int ssw = scb ^ (srow & 7);
  const ushort_t* aS = Ab + (size_t)(bm0 + srow) * lda + ssw * 8;
  const ushort_t* bS = Bb + (size_t)(bn0 + srow) * ldb + ssw * 8;

  auto stage_a = [&](int s, int kk) {
#pragma unroll
    for (int g = 0; g < 4; ++g)
      gload16(aS + (size_t)(g * 64) * lda + kk, &Al[s][g * 4096 + w * 512]);
  };
  auto stage_b = [&](int s, int kk) {
#pragma unroll
    for (int g = 0; g < 4; ++g)
      gload16(bS + (size_t)(g * 64) * ldb + kk, &Bl[s][g * 4096 + w * 512]);
  };

  f32x4 acc[8][4] = {};
  bf16x8 a_r[4][2], b_r[4][2];

  auto read_a = [&](int s, int mh) {
#pragma unroll
    for (int mi = 0; mi < 4; ++mi) {
      int row = wr * 128 + mh * 64 + mi * 16 + fr;
#pragma unroll
      for (int ks = 0; ks < 2; ++ks) {
        int blk = ((ks * 4 + fq) ^ (row & 7)) * 8;
        a_r[mi][ks] = *(const bf16x8*)&Al[s][row * 64 + blk];
      }
    }
  };
  auto read_b = [&](int s, int nh) {
#pragma unroll
    for (int ni = 0; ni < 2; ++ni) {
      int row = wc * 64 + nh * 32 + ni * 16 + fr;
#pragma unroll
      for (int ks = 0; ks < 2; ++ks) {
        int blk = ((ks * 4 + fq) ^ (row & 7)) * 8;
        b_r[nh * 2 + ni][ks] = *(const bf16x8*)&Bl[s][row * 64 + blk];
      }
    }
  };
  auto phase_mfma = [&](int mh, int nh) {
    __builtin_amdgcn_s_setprio(1);
#pragma unroll
    for (int ks = 0; ks < 2; ++ks)
#pragma unroll
      for (int mi = 0; mi < 4; ++mi)
#pragma unroll
        for (int ni = 0; ni < 2; ++ni)
          acc[mh * 4 + mi][nh * 2 + ni] =
              __builtin_amdgcn_mfma_f32_16x16x32_bf16(
                  a_r[mi][ks], b_r[nh * 2 + ni][ks],
                  acc[mh * 4 + mi][nh * 2 + ni], 0, 0, 0);
    __builtin_amdgcn_s_setprio(0);
  };

  const int nt = K >> 6;
  stage_b(0, 0);
  stage_a(0, 0);
  if (nt > 1) {
    stage_b(1, 64);
    stage_a(1, 64);
    asm volatile("s_waitcnt vmcnt(8)" ::: "memory");
  } else {
    asm volatile("s_waitcnt vmcnt(0)" ::: "memory");
  }
  __builtin_amdgcn_s_barrier();

  for (int t = 0; t < nt; ++t) {
    const int s = t & 1;
    const int kk2 = (t + 2) << 6;
    const bool st2 = (t + 2) < nt;
    read_a(s, 0);
    read_b(s, 0);
    __builtin_amdgcn_s_barrier();
    phase_mfma(0, 0);
    __builtin_amdgcn_s_barrier();
    read_b(s, 1);
    __builtin_amdgcn_s_barrier();
    phase_mfma(0, 1);
    __builtin_amdgcn_s_barrier();
    read_a(s, 1);
    asm volatile("" ::: "memory");
    if (st2) stage_b(s, kk2);
    __builtin_amdgcn_s_barrier();
    phase_mfma(1, 0);
    __builtin_amdgcn_s_barrier();
    asm volatile("" ::: "memory");
    if (st2) stage_a(s, kk2);
    __builtin_amdgcn_s_barrier();
    phase_mfma(1, 1);
    if (st2)
      asm volatile("s_waitcnt vmcnt(8)" ::: "memory");
    else if (t + 1 < nt)
      asm volatile("s_waitcnt vmcnt(0)" ::: "memory");
    __builtin_amdgcn_s_barrier();
  }

  const size_t cbase = (size_t)bz * sC;
#pragma unroll
  for (int mi = 0; mi < 8; ++mi) {
#pragma unroll
    for (int r = 0; r < 4; ++r) {
      int gm = bm0 + wr * 128 + mi * 16 + fq * 4 + r;
#pragma unroll
      for (int ni = 0; ni < 4; ++ni) {
        int gn = bn0 + wc * 64 + ni * 16 + fr;
        float v = acc[mi][ni][r];
        size_t off = cbase + (size_t)gm * N + gn;
        if constexpr (EPI == 0) {
          ((ushort_t*)Cg)[off] = f2b(v + bias[gn]);
        } else if constexpr (EPI == 2) {
          ((ushort_t*)Cg)[off] = f2b(__expf(fminf(v * scale, 80.f)));
        }
      }
    }
  }

  if constexpr (EPI == 2) {
    float cm[4], cs4[4];
#pragma unroll
    for (int ni = 0; ni < 4; ++ni) {
      float m = -3e38f;
#pragma unroll
      for (int mi = 0; mi < 8; ++mi)
#pragma unroll
        for (int r = 0; r < 4; ++r) m = fmaxf(m, acc[mi][ni][r] * scale);
      m = fmaxf(m, __shfl_xor(m, 16));
      m = fmaxf(m, __shfl_xor(m, 32));
      float s = 0.f;
#pragma unroll
      for (int mi = 0; mi < 8; ++mi)
#pragma unroll
        for (int r = 0; r < 4; ++r) s += __expf(acc[mi][ni][r] * scale - m);
      s += __shfl_xor(s, 16);
      s += __shfl_xor(s, 32);
      cm[ni] = m;
      cs4[ni] = s;
    }
    __syncthreads();
    if (lane < 16) {
#pragma unroll
      for (int ni = 0; ni < 4; ++ni) {
        s_max[wr][wc * 64 + ni * 16 + lane] = cm[ni];
        s_sum[wr][wc * 64 + ni * 16 + lane] = cs4[ni];
      }
    }
    __syncthreads();
    if (tid < 256) {
      float m0 = s_max[0][tid], m1 = s_max[1][tid];
      float M = fmaxf(m0, m1);
      float S = s_sum[0][tid] * __expf(m0 - M) + s_sum[1][tid] * __expf(m1 - M);
      size_t o = (((size_t)bz * 16 + by) * 4096 + bn0 + tid) * 2;
      smp[o] = M;
      smp[o + 1] = S;
    }
  }
}

// ------- 128x128 dbuf GEMM, XCD-swizzled -------
// EPI: 3 bf16 *colsc[n]; 5 plain bf16
template <int EPI>
__global__ __launch_bounds__(256) void gemm_bt(
    const ushort_t* __restrict__ A, const ushort_t* __restrict__ B,
    void* __restrict__ Cg, const float* __restrict__ colsc, int N, int K,
    int lda, int ldb, size_t sA, size_t sB, size_t sC) {
  __shared__ __align__(16) ushort_t As[2][4096];
  __shared__ __align__(16) ushort_t Bs[2][4096];
  int bx, by, bz;
  xcd_swz(bx, by, bz);
  const ushort_t* Ab = A + bz * sA;
  const ushort_t* Bb = B + bz * sB;
  const int bm0 = by * 128, bn0 = bx * 128;
  const int tid = threadIdx.x;
  const int w = tid >> 6, lane = tid & 63;
  const int sm = tid >> 2, sk = (tid & 3) * 8;
  const ushort_t* aS = Ab + (size_t)(bm0 + sm) * lda + sk;
  const ushort_t* bS = Bb + (size_t)(bn0 + sm) * ldb + sk;
  const int wm = (w >> 1) * 64, wn = (w & 1) * 64;
  const int fr = lane & 15, fk = (lane >> 4) * 8;
  f32x4 acc[4][4] = {};

  auto stage = [&](int buf, int kk) {
    ushort_t* la = &As[buf][w * 512];
    ushort_t* lb = &Bs[buf][w * 512];
    gload16(aS + kk, la);
    gload16(aS + (size_t)64 * lda + kk, la + 2048);
    gload16(bS + kk, lb);
    gload16(bS + (size_t)64 * ldb + kk, lb + 2048);
  };

  stage(0, 0);
  __syncthreads();
  const int nt = K >> 5;
  for (int t = 0; t < nt; ++t) {
    const int cur = t & 1;
    if (t + 1 < nt) stage(cur ^ 1, (t + 1) << 5);
    bf16x8 af[4], bfv[4];
#pragma unroll
    for (int mi = 0; mi < 4; mi++)
      af[mi] = *(const bf16x8*)&As[cur][(wm + mi * 16 + fr) * 32 + fk];
#pragma unroll
    for (int ni = 0; ni < 4; ni++)
      bfv[ni] = *(const bf16x8*)&Bs[cur][(wn + ni * 16 + fr) * 32 + fk];
#pragma unroll
    for (int mi = 0; mi < 4; mi++)
#pragma unroll
      for (int ni = 0; ni < 4; ni++)
        acc[mi][ni] = __builtin_amdgcn_mfma_f32_16x16x32_bf16(
            af[mi], bfv[ni], acc[mi][ni], 0, 0, 0);
    __syncthreads();
  }

  const int r0 = (lane >> 4) * 4;
  const size_t cbase = (size_t)bz * sC;
#pragma unroll
  for (int mi = 0; mi < 4; mi++) {
#pragma unroll
    for (int r = 0; r < 4; r++) {
      int gm = bm0 + wm + mi * 16 + r0 + r;
#pragma unroll
      for (int ni = 0; ni < 4; ni++) {
        int gn = bn0 + wn + ni * 16 + fr;
        float v = acc[mi][ni][r];
        size_t off = cbase + (size_t)gm * N + gn;
        if constexpr (EPI == 3) {
          ((ushort_t*)Cg)[off] = f2b(v * colsc[(size_t)bz * 4096 + gn]);
        } else {
          ((ushort_t*)Cg)[off] = f2b(v);
        }
      }
    }
  }
}

// -------- softmax finalize: alpha_j = exp(-M_j)/S_j from 16 partials --------
__global__ __launch_bounds__(256) void sm_fin(const float* __restrict__ part,
                                              float* __restrict__ alpha) {
  int idx = blockIdx.x * 256 + threadIdx.x;  // b*4096 + j
  int b = idx >> 12, j = idx & 4095;
  float M = -3e38f, S = 0.f;
#pragma unroll
  for (int rc = 0; rc < 16; rc++) {
    size_t o = (((size_t)b * 16 + rc) * 4096 + j) * 2;
    float mi = part[o], si = part[o + 1];
    float nm = fmaxf(M, mi);
    S = S * __expf(M - nm) + si * __expf(mi - nm);
    M = nm;
  }
  alpha[idx] = __expf(-M) / S;
}

// ------- finalize: out[b][o][p] = outT[b][p][o] + x + proj_b[o] -------
__global__ __launch_bounds__(256) void finalize(
    const ushort_t* __restrict__ outT, const float* __restrict__ x,
    const float* __restrict__ pb, float* __restrict__ out) {
  __shared__ ushort_t tile[64][72];
  const int b = blockIdx.z;
  const int p0 = blockIdx.x * 64, o0 = blockIdx.y * 64;
  const int tid = threadIdx.x;
  const int tp = tid >> 2, to = (tid & 3) * 16;
  const ushort8* src =
      (const ushort8*)(outT + ((size_t)b * 4096 + p0 + tp) * 512 + o0 + to);
  ushort8 u0 = src[0], u1 = src[1];
  *(ushort8*)&tile[tp][to] = u0;
  *(ushort8*)&tile[tp][to + 8] = u1;
  __syncthreads();
  const int wo = tid >> 2, wp = (tid & 3) * 16;
  float bias = pb[o0 + wo];
  const float* xr = x + ((size_t)b * 512 + o0 + wo) * 4096 + p0 + wp;
  float* orow = out + ((size_t)b * 512 + o0 + wo) * 4096 + p0 + wp;
#pragma unroll
  for (int e = 0; e < 16; ++e)
    orow[e] = b2f(tile[wp + e][wo]) + xr[e] + bias;
}

extern "C" void kernel_launch(void* const* d_in, const int* in_sizes, int n_in,
                              void* d_out, int out_size, void* d_ws,
                              size_t ws_size, hipStream_t stream) {
  const float* x = (const float*)d_in[0];
  const float* gn_w = (const float*)d_in[1];
  const float* gn_b = (const float*)d_in[2];
  const float* qkv_w = (const float*)d_in[3];
  const float* qkv_b = (const float*)d_in[4];
  const float* proj_w = (const float*)d_in[5];
  const float* proj_b = (const float*)d_in[6];
  float* out = (float*)d_out;

  char* ws = (char*)d_ws;
  ushort_t* xnT   = (ushort_t*)(ws);              //  8 MB [p][c] (dead after QKV)
  ushort_t* Wpp   = (ushort_t*)(ws);              //  reuse: W''[b][o][j] 8 MB
  ushort_t* qkvw  = (ushort_t*)(ws + 8388608);
  ushort_t* projw = (ushort_t*)(ws + 9961472);
  float*    stats = (float*)(ws + 10485760);
  ushort_t* qkvT  = (ushort_t*)(ws + 10486272);   // 25 MB [p][1536] (dead after W'')
  ushort_t* outT  = (ushort_t*)(ws + 10486272);   // reuse: 8 MB [b][p][o]
  ushort_t* P     = (ushort_t*)(ws + 35652096);   // 64 MB [io][j] = exp(L)
  float*    smp   = (float*)(ws + 102760960);     //  1 MB (16 partials/col)
  float*    alpha = (float*)(ws + 104858112);     //  32 KB

  const float scale = 0.04419417382415922f;  // 1/sqrt(512)
  const size_t sXN = 2097152, sQKV = (size_t)4096 * 1536, sP = 16777216;

  prep_weights<<<4096, 256, 0, stream>>>(qkv_w, proj_w, qkvw, projw);
  gn_stats<<<64, 256, 0, stream>>>(x, stats);
  gn_apply_t<<<dim3(64, 8, 2), 256, 0, stream>>>(x, gn_w, gn_b, stats, xnT);
  // qkvT[p][o] = sum_c xnT[p][c]*qkvw[o][c] + qkv_b[o]  (M=8192 both batches)
  gemm8<0><<<dim3(6, 32, 1), 512, 0, stream>>>(
      xnT, qkvw, qkvT, qkv_b, nullptr, 1536, 512, 512, 512, 0, 0, 0, 1.f);
  // P[io][j] = exp(scale * qT[io].kT[j]) ; fused column stats (16 chunks)
  gemm8<2><<<dim3(16, 16, 2), 512, 0, stream>>>(
      qkvT, qkvT + 512, P, nullptr, smp, 4096, 512, 1536, 1536, sQKV, sQKV,
      sP, scale);
  sm_fin<<<32, 256, 0, stream>>>(smp, alpha);
  // W''[o][j] = alpha_j * sum_c projw[o][c]*vT[j][c]
  gemm_bt<3><<<dim3(32, 4, 2), 256, 0, stream>>>(
      projw, qkvT + 1024, Wpp, alpha, 4096, 512, 512, 1536, 0, sQKV, sXN);
  // outT[p][o] = sum_j P[p][j]*W''[o][j]   (deep K=4096, no atomics)
  gemm_bt<5><<<dim3(4, 32, 2), 256, 0, stream>>>(
      P, Wpp, outT, nullptr, 512, 4096, 4096, 4096, sP, sXN, sXN);
  // out[o][p] = outT[p][o] + x + proj_b[o]
  finalize<<<dim3(64, 8, 2), 256, 0, stream>>>(outT, x, proj_b, out);
}

// Round 7
// 190.366 us; speedup vs baseline: 1.5518x; 1.1264x over previous
//
#include <hip/hip_runtime.h>
#include <hip/hip_bf16.h>
#include <math.h>

typedef unsigned short ushort_t;
typedef __attribute__((ext_vector_type(8))) unsigned short ushort8;
typedef __attribute__((ext_vector_type(8))) __bf16 bf16x8;
typedef __attribute__((ext_vector_type(4))) float f32x4;

__device__ inline ushort_t f2b(float f) {
  __hip_bfloat16 h = __float2bfloat16(f);
  return __builtin_bit_cast(ushort_t, h);
}
__device__ inline float b2f(ushort_t u) {
  __hip_bfloat16 h = __builtin_bit_cast(__hip_bfloat16, u);
  return __bfloat162float(h);
}

__device__ inline void gload16(const ushort_t* g, ushort_t* l) {
  __builtin_amdgcn_global_load_lds(
      (const __attribute__((address_space(1))) unsigned int*)g,
      (__attribute__((address_space(3))) unsigned int*)l, 16, 0, 0);
}

// bijective XCD swizzle (m204)
__device__ inline void xcd_swz(int& bx, int& by, int& bz) {
  const int nx = gridDim.x, ny = gridDim.y;
  const int nwg = nx * ny * gridDim.z;
  const int orig = blockIdx.x + nx * (blockIdx.y + ny * blockIdx.z);
  const int q = nwg >> 3, r = nwg & 7, xcd = orig & 7, loc = orig >> 3;
  const int wg = (xcd < r ? xcd * (q + 1) : r * (q + 1) + (xcd - r) * q) + loc;
  bx = wg % nx;
  by = (wg / nx) % ny;
  bz = wg / (nx * ny);
}

// ---------------- weights fp32 -> bf16 ----------------
__global__ __launch_bounds__(256) void prep_weights(
    const float* __restrict__ qkv_w, const float* __restrict__ proj_w,
    ushort_t* __restrict__ qkvw, ushort_t* __restrict__ projw) {
  int idx = blockIdx.x * 256 + threadIdx.x;
  const int NQ = 1536 * 512;
  if (idx < NQ) {
    qkvw[idx] = f2b(qkv_w[idx]);
  } else {
    int j = idx - NQ;
    if (j < 512 * 512) projw[j] = f2b(proj_w[j]);
  }
}

// ---------------- GN stats ----------------
__global__ __launch_bounds__(256) void gn_stats(const float* __restrict__ x,
                                                float* __restrict__ stats) {
  const int tid = threadIdx.x;
  const int bg = blockIdx.x;
  const float4* xv = (const float4*)(x + (size_t)bg * 65536);
  float s = 0.f, ss = 0.f;
  for (int i = tid; i < 16384; i += 256) {
    float4 v = xv[i];
    s += v.x + v.y + v.z + v.w;
    ss += v.x * v.x + v.y * v.y + v.z * v.z + v.w * v.w;
  }
  __shared__ float red[8];
  for (int off = 32; off > 0; off >>= 1) {
    s += __shfl_down(s, off);
    ss += __shfl_down(ss, off);
  }
  if ((tid & 63) == 0) { red[tid >> 6] = s; red[4 + (tid >> 6)] = ss; }
  __syncthreads();
  if (tid == 0) {
    float st = red[0] + red[1] + red[2] + red[3];
    float sst = red[4] + red[5] + red[6] + red[7];
    float mean = st * (1.f / 65536.f);
    float var = sst * (1.f / 65536.f) - mean * mean;
    stats[bg * 2] = mean;
    stats[bg * 2 + 1] = rsqrtf(var + 1e-6f);
  }
}

// ---------------- GN apply + transpose ----------------
__global__ __launch_bounds__(256) void gn_apply_t(
    const float* __restrict__ x, const float* __restrict__ w,
    const float* __restrict__ bgn, const float* __restrict__ stats,
    ushort_t* __restrict__ xnT) {
  __shared__ ushort_t tile[64][68];
  const int b = blockIdx.z;
  const int p0 = blockIdx.x * 64, c0 = blockIdx.y * 64;
  const int tid = threadIdx.x;
  const float* xb = x + ((size_t)b * 512 + c0) * 4096 + p0;
  const int tc = tid >> 4, tp = (tid & 15) * 4;
#pragma unroll
  for (int pass = 0; pass < 4; ++pass) {
    int c = pass * 16 + tc;
    int cg = c0 + c;
    float mean = stats[(b * 32 + (cg >> 4)) * 2];
    float inv = stats[(b * 32 + (cg >> 4)) * 2 + 1];
    float wc = w[cg] * inv;
    float bc = bgn[cg] - mean * wc;
    float4 v = *(const float4*)(xb + (size_t)c * 4096 + tp);
    tile[c][tp] = f2b(v.x * wc + bc);
    tile[c][tp + 1] = f2b(v.y * wc + bc);
    tile[c][tp + 2] = f2b(v.z * wc + bc);
    tile[c][tp + 3] = f2b(v.w * wc + bc);
  }
  __syncthreads();
  const int c8 = (tid & 7) * 8;
#pragma unroll
  for (int pass = 0; pass < 2; ++pass) {
    int p = pass * 32 + (tid >> 3);
    ushort8 u;
#pragma unroll
    for (int e = 0; e < 8; ++e) u[e] = tile[c8 + e][p];
    *(ushort8*)(xnT + ((size_t)b * 4096 + p0 + p) * 512 + c0 + c8) = u;
  }
}

// ====== 256x256 8-phase bf16 GEMM, bt-form, XCD-swizzled ======
// EPI: 2 bf16 exp(v*scale) + column stats
template <int EPI>
__global__ __launch_bounds__(512, 2) void gemm8(
    const ushort_t* __restrict__ A, const ushort_t* __restrict__ B,
    void* __restrict__ Cg, const float* __restrict__ bias,
    float* __restrict__ smp, int N, int K, int lda, int ldb, size_t sA,
    size_t sB, size_t sC, float scale) {
  __shared__ __align__(16) ushort_t Al[2][256 * 64];
  __shared__ __align__(16) ushort_t Bl[2][256 * 64];
  __shared__ float s_max[2][256], s_sum[2][256];

  int bx, by, bz;
  xcd_swz(bx, by, bz);
  const ushort_t* Ab = A + bz * sA;
  const ushort_t* Bb = B + bz * sB;
  const int bm0 = by * 256, bn0 = bx * 256;
  const int tid = threadIdx.x;
  const int w = tid >> 6, lane = tid & 63;
  const int wr = w >> 2, wc = w & 3;
  const int fr = lane & 15, fq = lane >> 4;

  const int srow = tid >> 3, scb = tid & 7;
  const int ssw = scb ^ (srow & 7);
  const ushort_t* aS = Ab + (size_t)(bm0 + srow) * lda + ssw * 8;
  const ushort_t* bS = Bb + (size_t)(bn0 + srow) * ldb + ssw * 8;

  auto stage_a = [&](int s, int kk) {
#pragma unroll
    for (int g = 0; g < 4; ++g)
      gload16(aS + (size_t)(g * 64) * lda + kk, &Al[s][g * 4096 + w * 512]);
  };
  auto stage_b = [&](int s, int kk) {
#pragma unroll
    for (int g = 0; g < 4; ++g)
      gload16(bS + (size_t)(g * 64) * ldb + kk, &Bl[s][g * 4096 + w * 512]);
  };

  f32x4 acc[8][4] = {};
  bf16x8 a_r[4][2], b_r[4][2];

  auto read_a = [&](int s, int mh) {
#pragma unroll
    for (int mi = 0; mi < 4; ++mi) {
      int row = wr * 128 + mh * 64 + mi * 16 + fr;
#pragma unroll
      for (int ks = 0; ks < 2; ++ks) {
        int blk = ((ks * 4 + fq) ^ (row & 7)) * 8;
        a_r[mi][ks] = *(const bf16x8*)&Al[s][row * 64 + blk];
      }
    }
  };
  auto read_b = [&](int s, int nh) {
#pragma unroll
    for (int ni = 0; ni < 2; ++ni) {
      int row = wc * 64 + nh * 32 + ni * 16 + fr;
#pragma unroll
      for (int ks = 0; ks < 2; ++ks) {
        int blk = ((ks * 4 + fq) ^ (row & 7)) * 8;
        b_r[nh * 2 + ni][ks] = *(const bf16x8*)&Bl[s][row * 64 + blk];
      }
    }
  };
  auto phase_mfma = [&](int mh, int nh) {
    __builtin_amdgcn_s_setprio(1);
#pragma unroll
    for (int ks = 0; ks < 2; ++ks)
#pragma unroll
      for (int mi = 0; mi < 4; ++mi)
#pragma unroll
        for (int ni = 0; ni < 2; ++ni)
          acc[mh * 4 + mi][nh * 2 + ni] =
              __builtin_amdgcn_mfma_f32_16x16x32_bf16(
                  a_r[mi][ks], b_r[nh * 2 + ni][ks],
                  acc[mh * 4 + mi][nh * 2 + ni], 0, 0, 0);
    __builtin_amdgcn_s_setprio(0);
  };

  const int nt = K >> 6;
  stage_b(0, 0);
  stage_a(0, 0);
  if (nt > 1) {
    stage_b(1, 64);
    stage_a(1, 64);
    asm volatile("s_waitcnt vmcnt(8)" ::: "memory");
  } else {
    asm volatile("s_waitcnt vmcnt(0)" ::: "memory");
  }
  __builtin_amdgcn_s_barrier();

  for (int t = 0; t < nt; ++t) {
    const int s = t & 1;
    const int kk2 = (t + 2) << 6;
    const bool st2 = (t + 2) < nt;
    read_a(s, 0);
    read_b(s, 0);
    __builtin_amdgcn_s_barrier();
    phase_mfma(0, 0);
    __builtin_amdgcn_s_barrier();
    read_b(s, 1);
    __builtin_amdgcn_s_barrier();
    phase_mfma(0, 1);
    __builtin_amdgcn_s_barrier();
    read_a(s, 1);
    asm volatile("" ::: "memory");
    if (st2) stage_b(s, kk2);
    __builtin_amdgcn_s_barrier();
    phase_mfma(1, 0);
    __builtin_amdgcn_s_barrier();
    asm volatile("" ::: "memory");
    if (st2) stage_a(s, kk2);
    __builtin_amdgcn_s_barrier();
    phase_mfma(1, 1);
    if (st2)
      asm volatile("s_waitcnt vmcnt(8)" ::: "memory");
    else if (t + 1 < nt)
      asm volatile("s_waitcnt vmcnt(0)" ::: "memory");
    __builtin_amdgcn_s_barrier();
  }

  const size_t cbase = (size_t)bz * sC;
#pragma unroll
  for (int mi = 0; mi < 8; ++mi) {
#pragma unroll
    for (int r = 0; r < 4; ++r) {
      int gm = bm0 + wr * 128 + mi * 16 + fq * 4 + r;
#pragma unroll
      for (int ni = 0; ni < 4; ++ni) {
        int gn = bn0 + wc * 64 + ni * 16 + fr;
        float v = acc[mi][ni][r];
        size_t off = cbase + (size_t)gm * N + gn;
        ((ushort_t*)Cg)[off] = f2b(__expf(fminf(v * scale, 80.f)));
      }
    }
  }

  if constexpr (EPI == 2) {
    float cm[4], cs4[4];
#pragma unroll
    for (int ni = 0; ni < 4; ++ni) {
      float m = -3e38f;
#pragma unroll
      for (int mi = 0; mi < 8; ++mi)
#pragma unroll
        for (int r = 0; r < 4; ++r) m = fmaxf(m, acc[mi][ni][r] * scale);
      m = fmaxf(m, __shfl_xor(m, 16));
      m = fmaxf(m, __shfl_xor(m, 32));
      float s = 0.f;
#pragma unroll
      for (int mi = 0; mi < 8; ++mi)
#pragma unroll
        for (int r = 0; r < 4; ++r) s += __expf(acc[mi][ni][r] * scale - m);
      s += __shfl_xor(s, 16);
      s += __shfl_xor(s, 32);
      cm[ni] = m;
      cs4[ni] = s;
    }
    __syncthreads();
    if (lane < 16) {
#pragma unroll
      for (int ni = 0; ni < 4; ++ni) {
        s_max[wr][wc * 64 + ni * 16 + lane] = cm[ni];
        s_sum[wr][wc * 64 + ni * 16 + lane] = cs4[ni];
      }
    }
    __syncthreads();
    if (tid < 256) {
      float m0 = s_max[0][tid], m1 = s_max[1][tid];
      float M = fmaxf(m0, m1);
      float S = s_sum[0][tid] * __expf(m0 - M) + s_sum[1][tid] * __expf(m1 - M);
      size_t o = (((size_t)bz * 16 + by) * 4096 + bn0 + tid) * 2;
      smp[o] = M;
      smp[o + 1] = S;
    }
  }
}

// ====== 128x128 pipelined bf16 GEMM (BK=64, counted vmcnt, swizzled) ======
// C[m][n] = sum_k A[m][k]*B[n][k]
// EPI: 0 bf16 +bias[n]; 3 bf16 *colsc[n]; 5 plain bf16
template <int EPI>
__global__ __launch_bounds__(256) void gemm_pl(
    const ushort_t* __restrict__ A, const ushort_t* __restrict__ B,
    void* __restrict__ Cg, const float* __restrict__ bias,
    const float* __restrict__ colsc, int N, int K, int lda, int ldb,
    size_t sA, size_t sB, size_t sC) {
  __shared__ __align__(16) ushort_t Al[2][128 * 64];  // 16KB x2
  __shared__ __align__(16) ushort_t Bl[2][128 * 64];
  int bx, by, bz;
  xcd_swz(bx, by, bz);
  const ushort_t* Ab = A + bz * sA;
  const ushort_t* Bb = B + bz * sB;
  const int bm0 = by * 128, bn0 = bx * 128;
  const int tid = threadIdx.x;
  const int w = tid >> 6, lane = tid & 63;
  const int wm = (w >> 1) * 64, wn = (w & 1) * 64;
  const int fr = lane & 15, fq = lane >> 4;

  const int srow = tid >> 3, scb = tid & 7;
  const int ssw = scb ^ (srow & 7);
  const ushort_t* aS = Ab + (size_t)(bm0 + srow) * lda + ssw * 8;
  const ushort_t* bS = Bb + (size_t)(bn0 + srow) * ldb + ssw * 8;

  auto stage = [&](int s, int kk) {
#pragma unroll
    for (int g = 0; g < 4; ++g)
      gload16(aS + (size_t)(g * 32) * lda + kk, &Al[s][g * 2048 + w * 512]);
#pragma unroll
    for (int g = 0; g < 4; ++g)
      gload16(bS + (size_t)(g * 32) * ldb + kk, &Bl[s][g * 2048 + w * 512]);
  };

  f32x4 acc[4][4] = {};
  bf16x8 a_r[4][2], b_r[4][2];

  const int nt = K >> 6;
  stage(0, 0);
  if (nt > 1) {
    stage(1, 64);
    asm volatile("s_waitcnt vmcnt(8)" ::: "memory");
  } else {
    asm volatile("s_waitcnt vmcnt(0)" ::: "memory");
  }
  __builtin_amdgcn_s_barrier();

  for (int t = 0; t < nt; ++t) {
    const int s = t & 1;
    // P1: read all fragments of tile t
#pragma unroll
    for (int mi = 0; mi < 4; ++mi) {
      int row = wm + mi * 16 + fr;
#pragma unroll
      for (int ks = 0; ks < 2; ++ks) {
        int blk = ((ks * 4 + fq) ^ (row & 7)) * 8;
        a_r[mi][ks] = *(const bf16x8*)&Al[s][row * 64 + blk];
      }
    }
#pragma unroll
    for (int ni = 0; ni < 4; ++ni) {
      int row = wn + ni * 16 + fr;
#pragma unroll
      for (int ks = 0; ks < 2; ++ks) {
        int blk = ((ks * 4 + fq) ^ (row & 7)) * 8;
        b_r[ni][ks] = *(const bf16x8*)&Bl[s][row * 64 + blk];
      }
    }
    __builtin_amdgcn_s_barrier();
    __builtin_amdgcn_s_setprio(1);
#pragma unroll
    for (int ks = 0; ks < 2; ++ks)
#pragma unroll
      for (int mi = 0; mi < 4; ++mi)
#pragma unroll
        for (int ni = 0; ni < 2; ++ni)
          acc[mi][ni] = __builtin_amdgcn_mfma_f32_16x16x32_bf16(
              a_r[mi][ks], b_r[ni][ks], acc[mi][ni], 0, 0, 0);
    __builtin_amdgcn_s_setprio(0);
    __builtin_amdgcn_s_barrier();  // all waves done reading slot s
    // P2: stage tile t+2 into slot s; MFMA second half; counted gate
    if (t + 2 < nt) stage(s, (t + 2) << 6);
    __builtin_amdgcn_s_setprio(1);
#pragma unroll
    for (int ks = 0; ks < 2; ++ks)
#pragma unroll
      for (int mi = 0; mi < 4; ++mi)
#pragma unroll
        for (int ni = 2; ni < 4; ++ni)
          acc[mi][ni] = __builtin_amdgcn_mfma_f32_16x16x32_bf16(
              a_r[mi][ks], b_r[ni][ks], acc[mi][ni], 0, 0, 0);
    __builtin_amdgcn_s_setprio(0);
    if (t + 2 < nt)
      asm volatile("s_waitcnt vmcnt(8)" ::: "memory");
    else if (t + 1 < nt)
      asm volatile("s_waitcnt vmcnt(0)" ::: "memory");
    __builtin_amdgcn_s_barrier();
  }

  const int r0 = (lane >> 4) * 4;
  const size_t cbase = (size_t)bz * sC;
#pragma unroll
  for (int mi = 0; mi < 4; mi++) {
#pragma unroll
    for (int r = 0; r < 4; r++) {
      int gm = bm0 + wm + mi * 16 + r0 + r;
#pragma unroll
      for (int ni = 0; ni < 4; ni++) {
        int gn = bn0 + wn + ni * 16 + fr;
        float v = acc[mi][ni][r];
        size_t off = cbase + (size_t)gm * N + gn;
        if constexpr (EPI == 0) {
          ((ushort_t*)Cg)[off] = f2b(v + bias[gn]);
        } else if constexpr (EPI == 3) {
          ((ushort_t*)Cg)[off] = f2b(v * colsc[(size_t)bz * 4096 + gn]);
        } else {
          ((ushort_t*)Cg)[off] = f2b(v);
        }
      }
    }
  }
}

// -------- softmax finalize: alpha_j = exp(-M_j)/S_j from 16 partials --------
__global__ __launch_bounds__(256) void sm_fin(const float* __restrict__ part,
                                              float* __restrict__ alpha) {
  int idx = blockIdx.x * 256 + threadIdx.x;  // b*4096 + j
  int b = idx >> 12, j = idx & 4095;
  float M = -3e38f, S = 0.f;
#pragma unroll
  for (int rc = 0; rc < 16; rc++) {
    size_t o = (((size_t)b * 16 + rc) * 4096 + j) * 2;
    float mi = part[o], si = part[o + 1];
    float nm = fmaxf(M, mi);
    S = S * __expf(M - nm) + si * __expf(mi - nm);
    M = nm;
  }
  alpha[idx] = __expf(-M) / S;
}

// ------- finalize: out[b][o][p] = outT[b][p][o] + x + proj_b[o] -------
__global__ __launch_bounds__(256) void finalize(
    const ushort_t* __restrict__ outT, const float* __restrict__ x,
    const float* __restrict__ pb, float* __restrict__ out) {
  __shared__ ushort_t tile[64][72];
  const int b = blockIdx.z;
  const int p0 = blockIdx.x * 64, o0 = blockIdx.y * 64;
  const int tid = threadIdx.x;
  const int tp = tid >> 2, to = (tid & 3) * 16;
  const ushort8* src =
      (const ushort8*)(outT + ((size_t)b * 4096 + p0 + tp) * 512 + o0 + to);
  ushort8 u0 = src[0], u1 = src[1];
  *(ushort8*)&tile[tp][to] = u0;
  *(ushort8*)&tile[tp][to + 8] = u1;
  __syncthreads();
  const int wo = tid >> 2, wp = (tid & 3) * 16;
  float bias = pb[o0 + wo];
  const float* xr = x + ((size_t)b * 512 + o0 + wo) * 4096 + p0 + wp;
  float* orow = out + ((size_t)b * 512 + o0 + wo) * 4096 + p0 + wp;
#pragma unroll
  for (int e = 0; e < 16; ++e)
    orow[e] = b2f(tile[wp + e][wo]) + xr[e] + bias;
}

extern "C" void kernel_launch(void* const* d_in, const int* in_sizes, int n_in,
                              void* d_out, int out_size, void* d_ws,
                              size_t ws_size, hipStream_t stream) {
  const float* x = (const float*)d_in[0];
  const float* gn_w = (const float*)d_in[1];
  const float* gn_b = (const float*)d_in[2];
  const float* qkv_w = (const float*)d_in[3];
  const float* qkv_b = (const float*)d_in[4];
  const float* proj_w = (const float*)d_in[5];
  const float* proj_b = (const float*)d_in[6];
  float* out = (float*)d_out;

  char* ws = (char*)d_ws;
  ushort_t* xnT   = (ushort_t*)(ws);              //  8 MB [p][c] (dead after QKV)
  ushort_t* Wpp   = (ushort_t*)(ws);              //  reuse: W''[b][o][j] 8 MB
  ushort_t* qkvw  = (ushort_t*)(ws + 8388608);
  ushort_t* projw = (ushort_t*)(ws + 9961472);
  float*    stats = (float*)(ws + 10485760);
  ushort_t* qkvT  = (ushort_t*)(ws + 10486272);   // 25 MB [p][1536] (dead after W'')
  ushort_t* outT  = (ushort_t*)(ws + 10486272);   // reuse: 8 MB [b][p][o]
  ushort_t* P     = (ushort_t*)(ws + 35652096);   // 64 MB [io][j] = exp(L)
  float*    smp   = (float*)(ws + 102760960);     //  1 MB (16 partials/col)
  float*    alpha = (float*)(ws + 104858112);     //  32 KB

  const float scale = 0.04419417382415922f;  // 1/sqrt(512)
  const size_t sXN = 2097152, sQKV = (size_t)4096 * 1536, sP = 16777216;

  prep_weights<<<4096, 256, 0, stream>>>(qkv_w, proj_w, qkvw, projw);
  gn_stats<<<64, 256, 0, stream>>>(x, stats);
  gn_apply_t<<<dim3(64, 8, 2), 256, 0, stream>>>(x, gn_w, gn_b, stats, xnT);
  // qkvT[p][o] = sum_c xnT[p][c]*qkvw[o][c] + qkv_b[o]  (M=8192 both batches)
  gemm_pl<0><<<dim3(12, 64, 1), 256, 0, stream>>>(
      xnT, qkvw, qkvT, qkv_b, nullptr, 1536, 512, 512, 512, 0, 0, 0);
  // P[io][j] = exp(scale * qT[io].kT[j]) ; fused column stats (16 chunks)
  gemm8<2><<<dim3(16, 16, 2), 512, 0, stream>>>(
      qkvT, qkvT + 512, P, nullptr, smp, 4096, 512, 1536, 1536, sQKV, sQKV,
      sP, scale);
  sm_fin<<<32, 256, 0, stream>>>(smp, alpha);
  // W''[o][j] = alpha_j * sum_c projw[o][c]*vT[j][c]
  gemm_pl<3><<<dim3(32, 4, 2), 256, 0, stream>>>(
      projw, qkvT + 1024, Wpp, nullptr, alpha, 4096, 512, 512, 1536, 0, sQKV,
      sXN);
  // outT[p][o] = sum_j P[p][j]*W''[o][j]   (deep K=4096, pipelined)
  gemm_pl<5><<<dim3(4, 32, 2), 256, 0, stream>>>(
      P, Wpp, outT, nullptr, nullptr, 512, 4096, 4096, 4096, sP, sXN, sXN);
  // out[o][p] = outT[p][o] + x + proj_b[o]
  finalize<<<dim3(64, 8, 2), 256, 0, stream>>>(outT, x, proj_b, out);
}

// Round 8
// 171.674 us; speedup vs baseline: 1.7208x; 1.1089x over previous
//
#include <hip/hip_runtime.h>
#include <hip/hip_bf16.h>
#include <math.h>

typedef unsigned short ushort_t;
typedef __attribute__((ext_vector_type(8))) unsigned short ushort8;
typedef __attribute__((ext_vector_type(8))) __bf16 bf16x8;
typedef __attribute__((ext_vector_type(4))) float f32x4;

__device__ inline ushort_t f2b(float f) {
  __hip_bfloat16 h = __float2bfloat16(f);
  return __builtin_bit_cast(ushort_t, h);
}
__device__ inline float b2f(ushort_t u) {
  __hip_bfloat16 h = __builtin_bit_cast(__hip_bfloat16, u);
  return __bfloat162float(h);
}

__device__ inline void gload16(const ushort_t* g, ushort_t* l) {
  __builtin_amdgcn_global_load_lds(
      (const __attribute__((address_space(1))) unsigned int*)g,
      (__attribute__((address_space(3))) unsigned int*)l, 16, 0, 0);
}

// bijective XCD swizzle (m204)
__device__ inline void xcd_swz(int& bx, int& by, int& bz) {
  const int nx = gridDim.x, ny = gridDim.y;
  const int nwg = nx * ny * gridDim.z;
  const int orig = blockIdx.x + nx * (blockIdx.y + ny * blockIdx.z);
  const int q = nwg >> 3, r = nwg & 7, xcd = orig & 7, loc = orig >> 3;
  const int wg = (xcd < r ? xcd * (q + 1) : r * (q + 1) + (xcd - r) * q) + loc;
  bx = wg % nx;
  by = (wg / nx) % ny;
  bz = wg / (nx * ny);
}

// ---------------- weights fp32 -> bf16 ----------------
__global__ __launch_bounds__(256) void prep_weights(
    const float* __restrict__ qkv_w, const float* __restrict__ proj_w,
    ushort_t* __restrict__ qkvw, ushort_t* __restrict__ projw) {
  int idx = blockIdx.x * 256 + threadIdx.x;
  const int NQ = 1536 * 512;
  if (idx < NQ) {
    qkvw[idx] = f2b(qkv_w[idx]);
  } else {
    int j = idx - NQ;
    if (j < 512 * 512) projw[j] = f2b(proj_w[j]);
  }
}

// ---------------- GN stats ----------------
__global__ __launch_bounds__(256) void gn_stats(const float* __restrict__ x,
                                                float* __restrict__ stats) {
  const int tid = threadIdx.x;
  const int bg = blockIdx.x;
  const float4* xv = (const float4*)(x + (size_t)bg * 65536);
  float s = 0.f, ss = 0.f;
  for (int i = tid; i < 16384; i += 256) {
    float4 v = xv[i];
    s += v.x + v.y + v.z + v.w;
    ss += v.x * v.x + v.y * v.y + v.z * v.z + v.w * v.w;
  }
  __shared__ float red[8];
  for (int off = 32; off > 0; off >>= 1) {
    s += __shfl_down(s, off);
    ss += __shfl_down(ss, off);
  }
  if ((tid & 63) == 0) { red[tid >> 6] = s; red[4 + (tid >> 6)] = ss; }
  __syncthreads();
  if (tid == 0) {
    float st = red[0] + red[1] + red[2] + red[3];
    float sst = red[4] + red[5] + red[6] + red[7];
    float mean = st * (1.f / 65536.f);
    float var = sst * (1.f / 65536.f) - mean * mean;
    stats[bg * 2] = mean;
    stats[bg * 2 + 1] = rsqrtf(var + 1e-6f);
  }
}

// ---------------- GN apply + transpose ----------------
__global__ __launch_bounds__(256) void gn_apply_t(
    const float* __restrict__ x, const float* __restrict__ w,
    const float* __restrict__ bgn, const float* __restrict__ stats,
    ushort_t* __restrict__ xnT) {
  __shared__ ushort_t tile[64][68];
  const int b = blockIdx.z;
  const int p0 = blockIdx.x * 64, c0 = blockIdx.y * 64;
  const int tid = threadIdx.x;
  const float* xb = x + ((size_t)b * 512 + c0) * 4096 + p0;
  const int tc = tid >> 4, tp = (tid & 15) * 4;
#pragma unroll
  for (int pass = 0; pass < 4; ++pass) {
    int c = pass * 16 + tc;
    int cg = c0 + c;
    float mean = stats[(b * 32 + (cg >> 4)) * 2];
    float inv = stats[(b * 32 + (cg >> 4)) * 2 + 1];
    float wc = w[cg] * inv;
    float bc = bgn[cg] - mean * wc;
    float4 v = *(const float4*)(xb + (size_t)c * 4096 + tp);
    tile[c][tp] = f2b(v.x * wc + bc);
    tile[c][tp + 1] = f2b(v.y * wc + bc);
    tile[c][tp + 2] = f2b(v.z * wc + bc);
    tile[c][tp + 3] = f2b(v.w * wc + bc);
  }
  __syncthreads();
  const int c8 = (tid & 7) * 8;
#pragma unroll
  for (int pass = 0; pass < 2; ++pass) {
    int p = pass * 32 + (tid >> 3);
    ushort8 u;
#pragma unroll
    for (int e = 0; e < 8; ++e) u[e] = tile[c8 + e][p];
    *(ushort8*)(xnT + ((size_t)b * 4096 + p0 + p) * 512 + c0 + c8) = u;
  }
}

// ====== 256x256 8-phase bf16 GEMM, bt-form, XCD-swizzled ======
// EPI 2: bf16 exp(v*scale) + column stats
template <int EPI>
__global__ __launch_bounds__(512, 2) void gemm8(
    const ushort_t* __restrict__ A, const ushort_t* __restrict__ B,
    void* __restrict__ Cg, const float* __restrict__ bias,
    float* __restrict__ smp, int N, int K, int lda, int ldb, size_t sA,
    size_t sB, size_t sC, float scale) {
  __shared__ __align__(16) ushort_t Al[2][256 * 64];
  __shared__ __align__(16) ushort_t Bl[2][256 * 64];
  __shared__ float s_max[2][256], s_sum[2][256];

  int bx, by, bz;
  xcd_swz(bx, by, bz);
  const ushort_t* Ab = A + bz * sA;
  const ushort_t* Bb = B + bz * sB;
  const int bm0 = by * 256, bn0 = bx * 256;
  const int tid = threadIdx.x;
  const int w = tid >> 6, lane = tid & 63;
  const int wr = w >> 2, wc = w & 3;
  const int fr = lane & 15, fq = lane >> 4;

  const int srow = tid >> 3, scb = tid & 7;
  const int ssw = scb ^ (srow & 7);
  const ushort_t* aS = Ab + (size_t)(bm0 + srow) * lda + ssw * 8;
  const ushort_t* bS = Bb + (size_t)(bn0 + srow) * ldb + ssw * 8;

  auto stage_a = [&](int s, int kk) {
#pragma unroll
    for (int g = 0; g < 4; ++g)
      gload16(aS + (size_t)(g * 64) * lda + kk, &Al[s][g * 4096 + w * 512]);
  };
  auto stage_b = [&](int s, int kk) {
#pragma unroll
    for (int g = 0; g < 4; ++g)
      gload16(bS + (size_t)(g * 64) * ldb + kk, &Bl[s][g * 4096 + w * 512]);
  };

  f32x4 acc[8][4] = {};
  bf16x8 a_r[4][2], b_r[4][2];

  auto read_a = [&](int s, int mh) {
#pragma unroll
    for (int mi = 0; mi < 4; ++mi) {
      int row = wr * 128 + mh * 64 + mi * 16 + fr;
#pragma unroll
      for (int ks = 0; ks < 2; ++ks) {
        int blk = ((ks * 4 + fq) ^ (row & 7)) * 8;
        a_r[mi][ks] = *(const bf16x8*)&Al[s][row * 64 + blk];
      }
    }
  };
  auto read_b = [&](int s, int nh) {
#pragma unroll
    for (int ni = 0; ni < 2; ++ni) {
      int row = wc * 64 + nh * 32 + ni * 16 + fr;
#pragma unroll
      for (int ks = 0; ks < 2; ++ks) {
        int blk = ((ks * 4 + fq) ^ (row & 7)) * 8;
        b_r[nh * 2 + ni][ks] = *(const bf16x8*)&Bl[s][row * 64 + blk];
      }
    }
  };
  auto phase_mfma = [&](int mh, int nh) {
    __builtin_amdgcn_s_setprio(1);
#pragma unroll
    for (int ks = 0; ks < 2; ++ks)
#pragma unroll
      for (int mi = 0; mi < 4; ++mi)
#pragma unroll
        for (int ni = 0; ni < 2; ++ni)
          acc[mh * 4 + mi][nh * 2 + ni] =
              __builtin_amdgcn_mfma_f32_16x16x32_bf16(
                  a_r[mi][ks], b_r[nh * 2 + ni][ks],
                  acc[mh * 4 + mi][nh * 2 + ni], 0, 0, 0);
    __builtin_amdgcn_s_setprio(0);
  };

  const int nt = K >> 6;
  stage_b(0, 0);
  stage_a(0, 0);
  if (nt > 1) {
    stage_b(1, 64);
    stage_a(1, 64);
    asm volatile("s_waitcnt vmcnt(8)" ::: "memory");
  } else {
    asm volatile("s_waitcnt vmcnt(0)" ::: "memory");
  }
  __builtin_amdgcn_s_barrier();

  for (int t = 0; t < nt; ++t) {
    const int s = t & 1;
    const int kk2 = (t + 2) << 6;
    const bool st2 = (t + 2) < nt;
    read_a(s, 0);
    read_b(s, 0);
    __builtin_amdgcn_s_barrier();
    phase_mfma(0, 0);
    __builtin_amdgcn_s_barrier();
    read_b(s, 1);
    __builtin_amdgcn_s_barrier();
    phase_mfma(0, 1);
    __builtin_amdgcn_s_barrier();
    read_a(s, 1);
    asm volatile("" ::: "memory");
    if (st2) stage_b(s, kk2);
    __builtin_amdgcn_s_barrier();
    phase_mfma(1, 0);
    __builtin_amdgcn_s_barrier();
    asm volatile("" ::: "memory");
    if (st2) stage_a(s, kk2);
    __builtin_amdgcn_s_barrier();
    phase_mfma(1, 1);
    if (st2)
      asm volatile("s_waitcnt vmcnt(8)" ::: "memory");
    else if (t + 1 < nt)
      asm volatile("s_waitcnt vmcnt(0)" ::: "memory");
    __builtin_amdgcn_s_barrier();
  }

  const size_t cbase = (size_t)bz * sC;
#pragma unroll
  for (int mi = 0; mi < 8; ++mi) {
#pragma unroll
    for (int r = 0; r < 4; ++r) {
      int gm = bm0 + wr * 128 + mi * 16 + fq * 4 + r;
#pragma unroll
      for (int ni = 0; ni < 4; ++ni) {
        int gn = bn0 + wc * 64 + ni * 16 + fr;
        float v = acc[mi][ni][r];
        size_t off = cbase + (size_t)gm * N + gn;
        ((ushort_t*)Cg)[off] = f2b(__expf(fminf(v * scale, 80.f)));
      }
    }
  }

  if constexpr (EPI == 2) {
    float cm[4], cs4[4];
#pragma unroll
    for (int ni = 0; ni < 4; ++ni) {
      float m = -3e38f;
#pragma unroll
      for (int mi = 0; mi < 8; ++mi)
#pragma unroll
        for (int r = 0; r < 4; ++r) m = fmaxf(m, acc[mi][ni][r] * scale);
      m = fmaxf(m, __shfl_xor(m, 16));
      m = fmaxf(m, __shfl_xor(m, 32));
      float s = 0.f;
#pragma unroll
      for (int mi = 0; mi < 8; ++mi)
#pragma unroll
        for (int r = 0; r < 4; ++r) s += __expf(acc[mi][ni][r] * scale - m);
      s += __shfl_xor(s, 16);
      s += __shfl_xor(s, 32);
      cm[ni] = m;
      cs4[ni] = s;
    }
    __syncthreads();
    if (lane < 16) {
#pragma unroll
      for (int ni = 0; ni < 4; ++ni) {
        s_max[wr][wc * 64 + ni * 16 + lane] = cm[ni];
        s_sum[wr][wc * 64 + ni * 16 + lane] = cs4[ni];
      }
    }
    __syncthreads();
    if (tid < 256) {
      float m0 = s_max[0][tid], m1 = s_max[1][tid];
      float M = fmaxf(m0, m1);
      float S = s_sum[0][tid] * __expf(m0 - M) + s_sum[1][tid] * __expf(m1 - M);
      size_t o = (((size_t)bz * 16 + by) * 4096 + bn0 + tid) * 2;
      smp[o] = M;
      smp[o + 1] = S;
    }
  }
}

// ====== 128x128 pipelined bf16 GEMM (BK=64, counted vmcnt, swizzled) ======
// C[m][n] = sum_k A[m][k]*B[n][k];  K = per-split contraction length
// EPI: 0 bf16 +bias[n]; 3 bf16 *colsc[n]; 5 plain bf16 (split partials)
template <int EPI, int SPLIT>
__global__ __launch_bounds__(256, 2) void gemm_pl(
    const ushort_t* __restrict__ A, const ushort_t* __restrict__ B,
    void* __restrict__ Cg, const float* __restrict__ bias,
    const float* __restrict__ colsc, int N, int K, int lda, int ldb,
    size_t sA, size_t sB, size_t sC, size_t sSp) {
  __shared__ __align__(16) ushort_t Al[2][128 * 64];  // 16KB x2
  __shared__ __align__(16) ushort_t Bl[2][128 * 64];
  int bx, by, bzt;
  xcd_swz(bx, by, bzt);
  const int bz = bzt / SPLIT, sp = bzt % SPLIT;
  const ushort_t* Ab = A + bz * sA + (size_t)sp * K;
  const ushort_t* Bb = B + bz * sB + (size_t)sp * K;
  const int bm0 = by * 128, bn0 = bx * 128;
  const int tid = threadIdx.x;
  const int w = tid >> 6, lane = tid & 63;
  const int wm = (w >> 1) * 64, wn = (w & 1) * 64;
  const int fr = lane & 15, fq = lane >> 4;

  const int srow = tid >> 3, scb = tid & 7;
  const int ssw = scb ^ (srow & 7);
  const ushort_t* aS = Ab + (size_t)(bm0 + srow) * lda + ssw * 8;
  const ushort_t* bS = Bb + (size_t)(bn0 + srow) * ldb + ssw * 8;

  auto stage = [&](int s, int kk) {
#pragma unroll
    for (int g = 0; g < 4; ++g)
      gload16(aS + (size_t)(g * 32) * lda + kk, &Al[s][g * 2048 + w * 512]);
#pragma unroll
    for (int g = 0; g < 4; ++g)
      gload16(bS + (size_t)(g * 32) * ldb + kk, &Bl[s][g * 2048 + w * 512]);
  };

  f32x4 acc[4][4] = {};
  bf16x8 a_r[4][2], b_r[4][2];

  const int nt = K >> 6;
  stage(0, 0);
  if (nt > 1) {
    stage(1, 64);
    asm volatile("s_waitcnt vmcnt(8)" ::: "memory");
  } else {
    asm volatile("s_waitcnt vmcnt(0)" ::: "memory");
  }
  __builtin_amdgcn_s_barrier();

  for (int t = 0; t < nt; ++t) {
    const int s = t & 1;
#pragma unroll
    for (int mi = 0; mi < 4; ++mi) {
      int row = wm + mi * 16 + fr;
#pragma unroll
      for (int ks = 0; ks < 2; ++ks) {
        int blk = ((ks * 4 + fq) ^ (row & 7)) * 8;
        a_r[mi][ks] = *(const bf16x8*)&Al[s][row * 64 + blk];
      }
    }
#pragma unroll
    for (int ni = 0; ni < 4; ++ni) {
      int row = wn + ni * 16 + fr;
#pragma unroll
      for (int ks = 0; ks < 2; ++ks) {
        int blk = ((ks * 4 + fq) ^ (row & 7)) * 8;
        b_r[ni][ks] = *(const bf16x8*)&Bl[s][row * 64 + blk];
      }
    }
    __builtin_amdgcn_s_barrier();
    __builtin_amdgcn_s_setprio(1);
#pragma unroll
    for (int ks = 0; ks < 2; ++ks)
#pragma unroll
      for (int mi = 0; mi < 4; ++mi)
#pragma unroll
        for (int ni = 0; ni < 2; ++ni)
          acc[mi][ni] = __builtin_amdgcn_mfma_f32_16x16x32_bf16(
              a_r[mi][ks], b_r[ni][ks], acc[mi][ni], 0, 0, 0);
    __builtin_amdgcn_s_setprio(0);
    __builtin_amdgcn_s_barrier();  // all waves done reading slot s
    if (t + 2 < nt) stage(s, (t + 2) << 6);
    __builtin_amdgcn_s_setprio(1);
#pragma unroll
    for (int ks = 0; ks < 2; ++ks)
#pragma unroll
      for (int mi = 0; mi < 4; ++mi)
#pragma unroll
        for (int ni = 2; ni < 4; ++ni)
          acc[mi][ni] = __builtin_amdgcn_mfma_f32_16x16x32_bf16(
              a_r[mi][ks], b_r[ni][ks], acc[mi][ni], 0, 0, 0);
    __builtin_amdgcn_s_setprio(0);
    if (t + 2 < nt)
      asm volatile("s_waitcnt vmcnt(8)" ::: "memory");
    else if (t + 1 < nt)
      asm volatile("s_waitcnt vmcnt(0)" ::: "memory");
    __builtin_amdgcn_s_barrier();
  }

  const int r0 = (lane >> 4) * 4;
  const size_t cbase = (size_t)sp * sSp + (size_t)bz * sC;
#pragma unroll
  for (int mi = 0; mi < 4; mi++) {
#pragma unroll
    for (int r = 0; r < 4; r++) {
      int gm = bm0 + wm + mi * 16 + r0 + r;
#pragma unroll
      for (int ni = 0; ni < 4; ni++) {
        int gn = bn0 + wn + ni * 16 + fr;
        float v = acc[mi][ni][r];
        size_t off = cbase + (size_t)gm * N + gn;
        if constexpr (EPI == 0) {
          ((ushort_t*)Cg)[off] = f2b(v + bias[gn]);
        } else if constexpr (EPI == 3) {
          ((ushort_t*)Cg)[off] = f2b(v * colsc[(size_t)bz * 4096 + gn]);
        } else {
          ((ushort_t*)Cg)[off] = f2b(v);
        }
      }
    }
  }
}

// -------- softmax finalize: alpha_j = exp(-M_j)/S_j from 16 partials --------
__global__ __launch_bounds__(256) void sm_fin(const float* __restrict__ part,
                                              float* __restrict__ alpha) {
  int idx = blockIdx.x * 256 + threadIdx.x;  // b*4096 + j
  int b = idx >> 12, j = idx & 4095;
  float M = -3e38f, S = 0.f;
#pragma unroll
  for (int rc = 0; rc < 16; rc++) {
    size_t o = (((size_t)b * 16 + rc) * 4096 + j) * 2;
    float mi = part[o], si = part[o + 1];
    float nm = fmaxf(M, mi);
    S = S * __expf(M - nm) + si * __expf(mi - nm);
    M = nm;
  }
  alpha[idx] = __expf(-M) / S;
}

// -- finalize: out[b][o][p] = part0[b][p][o] + part1[b][p][o] + x + proj_b --
__global__ __launch_bounds__(256) void finalize(
    const ushort_t* __restrict__ part, const float* __restrict__ x,
    const float* __restrict__ pb, float* __restrict__ out) {
  __shared__ float tile[64][68];
  const int b = blockIdx.z;
  const int p0 = blockIdx.x * 64, o0 = blockIdx.y * 64;
  const int tid = threadIdx.x;
  const int tp = tid >> 2, to = (tid & 3) * 16;
  const size_t base = ((size_t)b * 4096 + p0 + tp) * 512 + o0 + to;
  ushort8 u0 = *(const ushort8*)(part + base);
  ushort8 u1 = *(const ushort8*)(part + base + 8);
  ushort8 v0 = *(const ushort8*)(part + 4194304 + base);
  ushort8 v1 = *(const ushort8*)(part + 4194304 + base + 8);
#pragma unroll
  for (int e = 0; e < 8; ++e) {
    tile[tp][to + e] = b2f(u0[e]) + b2f(v0[e]);
    tile[tp][to + 8 + e] = b2f(u1[e]) + b2f(v1[e]);
  }
  __syncthreads();
  const int wo = tid >> 2, wp = (tid & 3) * 16;
  float bias = pb[o0 + wo];
  const float* xr = x + ((size_t)b * 512 + o0 + wo) * 4096 + p0 + wp;
  float* orow = out + ((size_t)b * 512 + o0 + wo) * 4096 + p0 + wp;
#pragma unroll
  for (int e = 0; e < 16; ++e)
    orow[e] = tile[wp + e][wo] + xr[e] + bias;
}

extern "C" void kernel_launch(void* const* d_in, const int* in_sizes, int n_in,
                              void* d_out, int out_size, void* d_ws,
                              size_t ws_size, hipStream_t stream) {
  const float* x = (const float*)d_in[0];
  const float* gn_w = (const float*)d_in[1];
  const float* gn_b = (const float*)d_in[2];
  const float* qkv_w = (const float*)d_in[3];
  const float* qkv_b = (const float*)d_in[4];
  const float* proj_w = (const float*)d_in[5];
  const float* proj_b = (const float*)d_in[6];
  float* out = (float*)d_out;

  char* ws = (char*)d_ws;
  ushort_t* xnT   = (ushort_t*)(ws);              //  8 MB [p][c] (dead after QKV)
  ushort_t* Wpp   = (ushort_t*)(ws);              //  reuse: W''[b][o][j] 8 MB
  ushort_t* qkvw  = (ushort_t*)(ws + 8388608);
  ushort_t* projw = (ushort_t*)(ws + 9961472);
  float*    stats = (float*)(ws + 10485760);
  ushort_t* qkvT  = (ushort_t*)(ws + 10486272);   // 25 MB [p][1536] (dead after W'')
  ushort_t* part  = (ushort_t*)(ws + 10486272);   // reuse: 2x8 MB split partials
  ushort_t* P     = (ushort_t*)(ws + 35652096);   // 64 MB [io][j] = exp(L)
  float*    smp   = (float*)(ws + 102760960);     //  1 MB (16 partials/col)
  float*    alpha = (float*)(ws + 104858112);     //  32 KB

  const float scale = 0.04419417382415922f;  // 1/sqrt(512)
  const size_t sXN = 2097152, sQKV = (size_t)4096 * 1536, sP = 16777216;

  prep_weights<<<4096, 256, 0, stream>>>(qkv_w, proj_w, qkvw, projw);
  gn_stats<<<64, 256, 0, stream>>>(x, stats);
  gn_apply_t<<<dim3(64, 8, 2), 256, 0, stream>>>(x, gn_w, gn_b, stats, xnT);
  // qkvT[p][o] = sum_c xnT[p][c]*qkvw[o][c] + qkv_b[o]  (M=8192 both batches)
  gemm_pl<0, 1><<<dim3(12, 64, 1), 256, 0, stream>>>(
      xnT, qkvw, qkvT, qkv_b, nullptr, 1536, 512, 512, 512, 0, 0, 0, 0);
  // P[io][j] = exp(scale * qT[io].kT[j]) ; fused column stats (16 chunks)
  gemm8<2><<<dim3(16, 16, 2), 512, 0, stream>>>(
      qkvT, qkvT + 512, P, nullptr, smp, 4096, 512, 1536, 1536, sQKV, sQKV,
      sP, scale);
  sm_fin<<<32, 256, 0, stream>>>(smp, alpha);
  // W''[o][j] = alpha_j * sum_c projw[o][c]*vT[j][c]
  gemm_pl<3, 1><<<dim3(32, 4, 2), 256, 0, stream>>>(
      projw, qkvT + 1024, Wpp, nullptr, alpha, 4096, 512, 512, 1536, 0, sQKV,
      sXN, 0);
  // part[sp][b][p][o] = sum_{j in half sp} P[p][j]*W''[o][j]  (split-K=2)
  gemm_pl<5, 2><<<dim3(4, 32, 4), 256, 0, stream>>>(
      P, Wpp, part, nullptr, nullptr, 512, 2048, 4096, 4096, sP, sXN, sXN,
      4194304);
  // out[o][p] = part0 + part1 + x + proj_b[o]
  finalize<<<dim3(64, 8, 2), 256, 0, stream>>>(part, x, proj_b, out);
}